// Round 8
// baseline (758.609 us; speedup 1.0000x reference)
//
#include <hip/hip_runtime.h>
#include <math.h>

#define B_ 256
#define L_ 256
#define V_ 2048
#define DIN_ 128
#define H_ 256
#define NODES_ 511

typedef _Float16 half8 __attribute__((ext_vector_type(8)));
typedef float f32x4 __attribute__((ext_vector_type(4)));

__device__ __forceinline__ float sigm(float x) { return 1.f / (1.f + __expf(-x)); }
__device__ __forceinline__ float tanh_f(float x) {
    float xc = fminf(fmaxf(x, -15.f), 15.f);
    float e = __expf(2.f * xc);
    return (e - 1.f) / (e + 1.f);
}
__device__ __forceinline__ void gload16(const void* g, void* l) {
    __builtin_amdgcn_global_load_lds((const __attribute__((address_space(1))) unsigned int*)g,
                                     (__attribute__((address_space(3))) unsigned int*)l, 16, 0, 0);
}

// WTh[n][k] fp16: h-part weights only. n = g*256+t (g:0=i,1=o,2=u,3=f0,4=f1), k:[0,256)=h1,[256,512)=h2
__global__ void build_WTh(_Float16* __restrict__ WTh,
    const float* __restrict__ Wiouh1, const float* __restrict__ Wfh11, const float* __restrict__ Wfh21,
    const float* __restrict__ Wiouh2, const float* __restrict__ Wfh12, const float* __restrict__ Wfh22)
{
    int e = blockIdx.x * 256 + threadIdx.x;   // < 1280*512
    int nn = e >> 9, k = e & 511;
    int g = nn >> 8, t = nn & 255;
    float v;
    if (k < 256) {
        v = (g < 3) ? Wiouh1[k * 768 + nn] : ((g == 3) ? Wfh11[k * 256 + t] : Wfh21[k * 256 + t]);
    } else {
        int kp = k - 256;
        v = (g < 3) ? Wiouh2[kp * 768 + nn] : ((g == 3) ? Wfh12[kp * 256 + t] : Wfh22[kp * 256 + t]);
    }
    WTh[e] = (_Float16)v;
}

// tab[id][col] f32 = emb(id,:) @ Wx_fused(:,col) + bias_total(col); emb row 0 zeroed.
__global__ __launch_bounds__(256) void build_table(float* __restrict__ tab, const float* __restrict__ emb,
    const float* __restrict__ Wioux, const float* __restrict__ Wfx,
    const float* __restrict__ bioux, const float* __restrict__ biouh1, const float* __restrict__ biouh2,
    const float* __restrict__ bfx, const float* __restrict__ bfh11, const float* __restrict__ bfh12,
    const float* __restrict__ bfh21, const float* __restrict__ bfh22)
{
    __shared__ float As[64][33];
    __shared__ float Ws[32][65];
    const int tid = threadIdx.x, tx = tid & 15, ty = tid >> 4;
    const int i0 = blockIdx.x * 64, c0 = blockIdx.y * 64;
    const int g = c0 >> 8;
    float acc[4][4];
    #pragma unroll
    for (int i = 0; i < 4; ++i)
        #pragma unroll
        for (int j = 0; j < 4; ++j) acc[i][j] = 0.f;

    for (int k0 = 0; k0 < 128; k0 += 32) {
        #pragma unroll
        for (int it = 0; it < 2; ++it) {
            int f = tid + it * 256;
            int row = f >> 3, kk = (f & 7) * 4;
            int gr = i0 + row;
            float4 av = (gr == 0) ? make_float4(0.f, 0.f, 0.f, 0.f)
                                  : *(const float4*)(emb + (size_t)gr * 128 + k0 + kk);
            As[row][kk] = av.x; As[row][kk + 1] = av.y; As[row][kk + 2] = av.z; As[row][kk + 3] = av.w;
            int k = f >> 4, cc = (f & 15) * 4;
            int col = c0 + cc;
            float4 wv = (g < 3) ? *(const float4*)(Wioux + (size_t)(k0 + k) * 768 + col)
                                : *(const float4*)(Wfx + (size_t)(k0 + k) * 256 + (col & 255));
            Ws[k][cc] = wv.x; Ws[k][cc + 1] = wv.y; Ws[k][cc + 2] = wv.z; Ws[k][cc + 3] = wv.w;
        }
        __syncthreads();
        #pragma unroll 8
        for (int k = 0; k < 32; ++k) {
            float a[4], w[4];
            #pragma unroll
            for (int i = 0; i < 4; ++i) a[i] = As[ty * 4 + i][k];
            #pragma unroll
            for (int j = 0; j < 4; ++j) w[j] = Ws[k][tx * 4 + j];
            #pragma unroll
            for (int i = 0; i < 4; ++i)
                #pragma unroll
                for (int j = 0; j < 4; ++j) acc[i][j] = fmaf(a[i], w[j], acc[i][j]);
        }
        __syncthreads();
    }
    #pragma unroll
    for (int j = 0; j < 4; ++j) {
        int col = c0 + tx * 4 + j; int t = col & 255;
        float bs = (g < 3) ? (bioux[col] + biouh1[col] + biouh2[col])
                 : (g == 3) ? (bfx[t] + bfh11[t] + bfh12[t])
                            : (bfx[t] + bfh21[t] + bfh22[t]);
        #pragma unroll
        for (int i = 0; i < 4; ++i)
            tab[(size_t)(i0 + ty * 4 + i) * 1280 + col] = acc[i][j] + bs;
    }
}

// Level-0 result depends only on token id: H0h/H0c[id][t]
__global__ void build_h0c0(const float* __restrict__ tab, _Float16* __restrict__ H0h, float* __restrict__ H0c) {
    int id = blockIdx.x, t = threadIdx.x;
    const float* tp = tab + (size_t)id * 1280 + t;
    float vi = sigm(tp[0]), vo = sigm(tp[256]), vu = tanh_f(tp[512]);
    float c = vi * vu;
    H0h[id * 256 + t] = (_Float16)(vo * tanh_f(c));
    H0c[id * 256 + t] = c;
}

// Tree-level cell v7: quarter-phase B staging (20KB LDS), R4-proven conflict-free
// LDS layout: Bs[s][nr][slot] with 64B rows; slot jj' holds global seg jj'^((nr>>1)&3).
// Block = 4 waves x (RT*16) rows x 16 t-cols x 5 gates. K=512 in 4 phases of 128.
// A: direct per-lane global loads (fragment layout), depth-2 register prefetch ring.
template<bool LVL1, int RT>
__global__ __launch_bounds__(256, 5) void cell7(
    const _Float16* __restrict__ WTh, const float* __restrict__ tab,
    const int* __restrict__ ids,
    const _Float16* __restrict__ h_prev, const float* __restrict__ c_prev,
    _Float16* __restrict__ h_out, float* __restrict__ c_out,
    int n, int ln, int off)
{
    constexpr int BM = RT * 64;
    __shared__ _Float16 Bs[1280 * 8];          // 20 KB: 1280 slots of 16B
    const int tid = threadIdx.x, lane = tid & 63, wid = tid >> 6;
    const int l15 = lane & 15, lg = lane >> 4;
    const int rowB = blockIdx.x * BM;
    const int t0 = blockIdx.y * 16;

    // ---- A source pointers per row-frag (k<256 -> aPA, k>=256 -> aPB)
    const _Float16* aPA[RT];
    const _Float16* aPB[RT];
    #pragma unroll
    for (int rt = 0; rt < RT; ++rt) {
        int row = rowB + wid * (RT * 16) + rt * 16 + l15;
        if constexpr (LVL1) {
            int b = row >> 7, j = row & 127;
            aPA[rt] = h_prev + (size_t)ids[b * NODES_ + 2 * j] * 256 + lg * 8;
            aPB[rt] = h_prev + (size_t)ids[b * NODES_ + 2 * j + 1] * 256 + lg * 8;
        } else {
            aPA[rt] = h_prev + (size_t)row * 512 + lg * 8;
            aPB[rt] = aPA[rt] + 256;
        }
    }

    // ---- B staging pointers (hoisted; per phase add kof). Thread owns slots f = tid + i*256.
    // Slot f -> s = f/320 (k-chunk within phase), nr = (f%320)>>2, jj' = f&3.
    // Slot holds global seg jj = jj' ^ ((nr>>1)&3)  [R4-proven conflict-free swizzle].
    const _Float16* sp[5];
    #pragma unroll
    for (int i = 0; i < 5; ++i) {
        int f = tid + i * 256;
        int s = f / 320, r = f - s * 320;
        int nr = r >> 2, jjp = r & 3;
        int jj = jjp ^ ((nr >> 1) & 3);
        int ng = (nr >> 4) * 256 + t0 + (nr & 15);
        sp[i] = WTh + (size_t)ng * 512 + s * 32 + jj * 8;
    }
    // stage phase 0
    #pragma unroll
    for (int i = 0; i < 5; ++i) gload16(sp[i], &Bs[(size_t)(tid + i * 256) * 8]);

    f32x4 acc[RT][5];
    #pragma unroll
    for (int rt = 0; rt < RT; ++rt)
        #pragma unroll
        for (int g = 0; g < 5; ++g) acc[rt][g] = (f32x4)0.f;

    // A prefetch ring, depth 2: slot S%3 holds step S
    half8 aF[3][RT];
    #pragma unroll
    for (int rt = 0; rt < RT; ++rt) aF[0][rt] = *(const half8*)(aPA[rt]);
    #pragma unroll
    for (int rt = 0; rt < RT; ++rt) aF[1][rt] = *(const half8*)(aPA[rt] + 32);

    __syncthreads();                            // phase-0 B staged

    #pragma unroll
    for (int p = 0; p < 4; ++p) {
        #pragma unroll
        for (int sl = 0; sl < 4; ++sl) {
            const int S = p * 4 + sl;           // global k-step, k = S*32
            const int pf = S + 2;
            if (pf < 16) {
                const int kpf = pf * 32;
                #pragma unroll
                for (int rt = 0; rt < RT; ++rt)
                    aF[pf % 3][rt] = (kpf < 256) ? *(const half8*)(aPA[rt] + kpf)
                                                 : *(const half8*)(aPB[rt] + (kpf - 256));
            }
            #pragma unroll
            for (int g = 0; g < 5; ++g) {
                int nr = g * 16 + l15;
                int slot = lg ^ ((nr >> 1) & 3);
                half8 bF = *(const half8*)&Bs[(size_t)(sl * 320 + nr * 4 + slot) * 8];
                #pragma unroll
                for (int rt = 0; rt < RT; ++rt)
                    acc[rt][g] = __builtin_amdgcn_mfma_f32_16x16x32_f16(aF[S % 3][rt], bF, acc[rt][g], 0, 0, 0);
            }
        }
        if (p < 3) {
            __syncthreads();                    // all phase-p LDS reads done
            const int kof = (p + 1) * 128;
            #pragma unroll
            for (int i = 0; i < 5; ++i) gload16(sp[i] + kof, &Bs[(size_t)(tid + i * 256) * 8]);
            __syncthreads();                    // phase-(p+1) B staged
        }
    }

    // ---- fused epilogue. D: col = lane&15, row = (lane>>4)*4 + q
    const int tcol = t0 + l15;
    #pragma unroll
    for (int rt = 0; rt < RT; ++rt) {
        #pragma unroll
        for (int q = 0; q < 4; ++q) {
            int row = rowB + wid * (RT * 16) + rt * 16 + lg * 4 + q;
            int b = row >> ln, j = row & (n - 1);
            int id = ids[b * NODES_ + off + j];
            const float* tp = tab + (size_t)id * 1280 + tcol;
            float c1, c2;
            if constexpr (LVL1) {
                int bb = row >> 7, jj = row & 127;
                c1 = c_prev[(size_t)ids[bb * NODES_ + 2 * jj] * 256 + tcol];
                c2 = c_prev[(size_t)ids[bb * NODES_ + 2 * jj + 1] * 256 + tcol];
            } else {
                const float* cpp = c_prev + (size_t)row * 512 + tcol;
                c1 = cpp[0]; c2 = cpp[256];
            }
            float vi  = sigm(acc[rt][0][q] + tp[0]);
            float vo  = sigm(acc[rt][1][q] + tp[256]);
            float vu  = tanh_f(acc[rt][2][q] + tp[512]);
            float vf0 = sigm(acc[rt][3][q] + tp[768]);
            float vf1 = sigm(acc[rt][4][q] + tp[1024]);
            float c = vi * vu + vf0 * c1 + vf1 * c2;
            size_t ob = (size_t)row * 256 + tcol;
            h_out[ob] = (_Float16)(vo * tanh_f(c));
            c_out[ob] = c;
        }
    }
}

// pred[b] = relu(h_root[b] @ Wl1 + bl1) @ Wl2 + bl2
__global__ void head_kernel(const _Float16* __restrict__ hroot,
    const float* __restrict__ Wl1, const float* __restrict__ bl1,
    const float* __restrict__ Wl2, const float* __restrict__ bl2,
    float* __restrict__ out)
{
    __shared__ float hrow[H_];
    __shared__ float red[256];
    int b = blockIdx.x; int tid = threadIdx.x;
    hrow[tid] = (float)hroot[(size_t)b * H_ + tid];
    __syncthreads();
    float v = 0.f;
    if (tid < 100) {
        float s = bl1[tid];
        for (int k = 0; k < H_; ++k) s = fmaf(hrow[k], Wl1[k * 100 + tid], s);
        v = fmaxf(s, 0.f) * Wl2[tid];
    }
    red[tid] = v;
    __syncthreads();
    for (int s = 128; s > 0; s >>= 1) { if (tid < s) red[tid] += red[tid + s]; __syncthreads(); }
    if (tid == 0) out[b] = red[0] + bl2[0];
}

extern "C" void kernel_launch(void* const* d_in, const int* in_sizes, int n_in,
                              void* d_out, int out_size, void* d_ws, size_t ws_size,
                              hipStream_t stream) {
    const int*   ids    = (const int*)d_in[0];
    const float* emb    = (const float*)d_in[1];
    const float* Wioux  = (const float*)d_in[2];
    const float* bioux  = (const float*)d_in[3];
    const float* Wiouh1 = (const float*)d_in[4];
    const float* biouh1 = (const float*)d_in[5];
    const float* Wiouh2 = (const float*)d_in[6];
    const float* biouh2 = (const float*)d_in[7];
    const float* Wfx    = (const float*)d_in[8];
    const float* bfx    = (const float*)d_in[9];
    const float* Wfh11  = (const float*)d_in[10];
    const float* bfh11  = (const float*)d_in[11];
    const float* Wfh12  = (const float*)d_in[12];
    const float* bfh12  = (const float*)d_in[13];
    const float* Wfh21  = (const float*)d_in[14];
    const float* bfh21  = (const float*)d_in[15];
    const float* Wfh22  = (const float*)d_in[16];
    const float* bfh22  = (const float*)d_in[17];
    const float* Wl1    = (const float*)d_in[18];
    const float* bl1    = (const float*)d_in[19];
    const float* Wl2    = (const float*)d_in[20];
    const float* bl2    = (const float*)d_in[21];
    float* out = (float*)d_out;

    // ws layout (bytes)
    char* wsb = (char*)d_ws;
    _Float16* WTh = (_Float16*)(wsb);                    //  1,310,720
    float*    tab = (float*)(wsb + 1310720);             // 10,485,760
    _Float16* H0h = (_Float16*)(wsb + 11796480);         //  1,048,576
    float*    H0c = (float*)(wsb + 12845056);            //  2,097,152
    _Float16* hA  = (_Float16*)(wsb + 14942208);         //  8,388,608  (lvl 2,4,6,8 out)
    _Float16* hB  = (_Float16*)(wsb + 23330816);         // 16,777,216  (lvl 1,3,5,7 out)
    float*    cA  = (float*)(wsb + 40108032);            // 16,777,216
    float*    cB  = (float*)(wsb + 56885248);            // 33,554,432  -> ends 90,439,680

    build_WTh<<<dim3(2560), 256, 0, stream>>>(WTh, Wiouh1, Wfh11, Wfh21, Wiouh2, Wfh12, Wfh22);
    build_table<<<dim3(32, 20), 256, 0, stream>>>(tab, emb, Wioux, Wfx,
        bioux, biouh1, biouh2, bfx, bfh11, bfh12, bfh21, bfh22);
    build_h0c0<<<dim3(2048), 256, 0, stream>>>(tab, H0h, H0c);

    // level 1: A gathered from id-indexed H0 tables
    cell7<true, 4><<<dim3(128, 16), 256, 0, stream>>>(WTh, tab, ids, H0h, H0c, hB, cB, 128, 7, 256);

    _Float16 *hp = hB, *hn = hA;
    float    *cp = cB, *cn = cA;
    int off = 384, n = 64, ln = 6;
    for (int lvl = 2; lvl <= 8; ++lvl) {
        int M = B_ * n;
        if (M >= 8192)
            cell7<false, 4><<<dim3(M / 256, 16), 256, 0, stream>>>(WTh, tab, ids, hp, cp, hn, cn, n, ln, off);
        else
            cell7<false, 2><<<dim3(M / 128, 16), 256, 0, stream>>>(WTh, tab, ids, hp, cp, hn, cn, n, ln, off);
        off += n; n >>= 1; --ln;
        _Float16* t1 = hp; hp = hn; hn = t1;
        float*    t2 = cp; cp = cn; cn = t2;
    }

    head_kernel<<<dim3(256), 256, 0, stream>>>(hp, Wl1, bl1, Wl2, bl2, out);
}

// Round 9
// 447.530 us; speedup vs baseline: 1.6951x; 1.6951x over previous
//
#include <hip/hip_runtime.h>
#include <math.h>

#define B_ 256
#define L_ 256
#define V_ 2048
#define DIN_ 128
#define H_ 256
#define NODES_ 511

typedef _Float16 half8 __attribute__((ext_vector_type(8)));
typedef float f32x4 __attribute__((ext_vector_type(4)));

__device__ __forceinline__ float sigm(float x) { return 1.f / (1.f + __expf(-x)); }
__device__ __forceinline__ float tanh_f(float x) {
    float xc = fminf(fmaxf(x, -15.f), 15.f);
    float e = __expf(2.f * xc);
    return (e - 1.f) / (e + 1.f);
}
__device__ __forceinline__ void gload16(const void* g, void* l) {
    __builtin_amdgcn_global_load_lds((const __attribute__((address_space(1))) unsigned int*)g,
                                     (__attribute__((address_space(3))) unsigned int*)l, 16, 0, 0);
}
__device__ __forceinline__ half8 gld8h(const _Float16* base, unsigned byteOff) {
    return *(const half8*)((const char*)base + byteOff);
}

// WTh[n][k] fp16: h-part weights only. n = g*256+t (g:0=i,1=o,2=u,3=f0,4=f1), k:[0,256)=h1,[256,512)=h2
__global__ void build_WTh(_Float16* __restrict__ WTh,
    const float* __restrict__ Wiouh1, const float* __restrict__ Wfh11, const float* __restrict__ Wfh21,
    const float* __restrict__ Wiouh2, const float* __restrict__ Wfh12, const float* __restrict__ Wfh22)
{
    int e = blockIdx.x * 256 + threadIdx.x;   // < 1280*512
    int nn = e >> 9, k = e & 511;
    int g = nn >> 8, t = nn & 255;
    float v;
    if (k < 256) {
        v = (g < 3) ? Wiouh1[k * 768 + nn] : ((g == 3) ? Wfh11[k * 256 + t] : Wfh21[k * 256 + t]);
    } else {
        int kp = k - 256;
        v = (g < 3) ? Wiouh2[kp * 768 + nn] : ((g == 3) ? Wfh12[kp * 256 + t] : Wfh22[kp * 256 + t]);
    }
    WTh[e] = (_Float16)v;
}

// tab[id][col] f32 = emb(id,:) @ Wx_fused(:,col) + bias_total(col); emb row 0 zeroed.
__global__ __launch_bounds__(256) void build_table(float* __restrict__ tab, const float* __restrict__ emb,
    const float* __restrict__ Wioux, const float* __restrict__ Wfx,
    const float* __restrict__ bioux, const float* __restrict__ biouh1, const float* __restrict__ biouh2,
    const float* __restrict__ bfx, const float* __restrict__ bfh11, const float* __restrict__ bfh12,
    const float* __restrict__ bfh21, const float* __restrict__ bfh22)
{
    __shared__ float As[64][33];
    __shared__ float Ws[32][65];
    const int tid = threadIdx.x, tx = tid & 15, ty = tid >> 4;
    const int i0 = blockIdx.x * 64, c0 = blockIdx.y * 64;
    const int g = c0 >> 8;
    float acc[4][4];
    #pragma unroll
    for (int i = 0; i < 4; ++i)
        #pragma unroll
        for (int j = 0; j < 4; ++j) acc[i][j] = 0.f;

    for (int k0 = 0; k0 < 128; k0 += 32) {
        #pragma unroll
        for (int it = 0; it < 2; ++it) {
            int f = tid + it * 256;
            int row = f >> 3, kk = (f & 7) * 4;
            int gr = i0 + row;
            float4 av = (gr == 0) ? make_float4(0.f, 0.f, 0.f, 0.f)
                                  : *(const float4*)(emb + (size_t)gr * 128 + k0 + kk);
            As[row][kk] = av.x; As[row][kk + 1] = av.y; As[row][kk + 2] = av.z; As[row][kk + 3] = av.w;
            int k = f >> 4, cc = (f & 15) * 4;
            int col = c0 + cc;
            float4 wv = (g < 3) ? *(const float4*)(Wioux + (size_t)(k0 + k) * 768 + col)
                                : *(const float4*)(Wfx + (size_t)(k0 + k) * 256 + (col & 255));
            Ws[k][cc] = wv.x; Ws[k][cc + 1] = wv.y; Ws[k][cc + 2] = wv.z; Ws[k][cc + 3] = wv.w;
        }
        __syncthreads();
        #pragma unroll 8
        for (int k = 0; k < 32; ++k) {
            float a[4], w[4];
            #pragma unroll
            for (int i = 0; i < 4; ++i) a[i] = As[ty * 4 + i][k];
            #pragma unroll
            for (int j = 0; j < 4; ++j) w[j] = Ws[k][tx * 4 + j];
            #pragma unroll
            for (int i = 0; i < 4; ++i)
                #pragma unroll
                for (int j = 0; j < 4; ++j) acc[i][j] = fmaf(a[i], w[j], acc[i][j]);
        }
        __syncthreads();
    }
    #pragma unroll
    for (int j = 0; j < 4; ++j) {
        int col = c0 + tx * 4 + j; int t = col & 255;
        float bs = (g < 3) ? (bioux[col] + biouh1[col] + biouh2[col])
                 : (g == 3) ? (bfx[t] + bfh11[t] + bfh12[t])
                            : (bfx[t] + bfh21[t] + bfh22[t]);
        #pragma unroll
        for (int i = 0; i < 4; ++i)
            tab[(size_t)(i0 + ty * 4 + i) * 1280 + col] = acc[i][j] + bs;
    }
}

// Level-0 result depends only on token id: H0h/H0c[id][t]
__global__ void build_h0c0(const float* __restrict__ tab, _Float16* __restrict__ H0h, float* __restrict__ H0c) {
    int id = blockIdx.x, t = threadIdx.x;
    const float* tp = tab + (size_t)id * 1280 + t;
    float vi = sigm(tp[0]), vo = sigm(tp[256]), vu = tanh_f(tp[512]);
    float c = vi * vu;
    H0h[id * 256 + t] = (_Float16)(vo * tanh_f(c));
    H0c[id * 256 + t] = c;
}

// Tree-level cell v8: full-K B residence in LDS (80KB), ZERO barriers in the K-loop.
// Block = 4 waves x (RT*16) rows x 16 t-cols x 5 gates. K=512 = 16 steps of 32.
// LDS layout: slot( srow = S*80+nr, jj' ) 16B units, 64B rows; slot jj' holds global
// k-seg jj'^((nr>>1)&3)  [R7-verified conflict-free on ds_read_b128].
// A: per-lane direct global loads (one instr each: 32-bit voffset + imm), depth-1 ring.
template<bool LVL1, int RT>
__global__ __launch_bounds__(256, 2) void cell8(
    const _Float16* __restrict__ WTh, const float* __restrict__ tab,
    const int* __restrict__ ids,
    const _Float16* __restrict__ h_prev, const float* __restrict__ c_prev,
    _Float16* __restrict__ h_out, float* __restrict__ c_out,
    int n, int ln, int off)
{
    constexpr int BM = RT * 64;
    __shared__ _Float16 Bs[5120 * 8];          // 80 KB: 5120 slots of 16B
    const int tid = threadIdx.x, lane = tid & 63, wid = tid >> 6;
    const int l15 = lane & 15, lg = lane >> 4;
    const int rowB = blockIdx.x * BM;
    const int t0 = blockIdx.y * 16;

    // ---- A byte-offsets per row-frag (32-bit; base pointer uniform)
    unsigned offA[RT];
    unsigned offB[LVL1 ? RT : 1];
    #pragma unroll
    for (int rt = 0; rt < RT; ++rt) {
        int row = rowB + wid * (RT * 16) + rt * 16 + l15;
        if constexpr (LVL1) {
            int b = row >> 7, j = row & 127;
            offA[rt] = (unsigned)ids[b * NODES_ + 2 * j] * 512u + lg * 16u;       // H0h row = 512B
            offB[rt] = (unsigned)ids[b * NODES_ + 2 * j + 1] * 512u + lg * 16u;
        } else {
            offA[rt] = (unsigned)row * 1024u + lg * 16u;                           // [h1|h2] row = 1024B
        }
    }

    // ---- stage full-K B slice: 5120 slots / 256 threads = 20 each (runtime loop, regs freed)
    for (int i = 0; i < 20; ++i) {
        int f = tid + i * 256;
        int srow = f >> 2, jjp = f & 3;
        int S = srow / 80, nr = srow - S * 80;
        int jj = jjp ^ ((nr >> 1) & 3);
        int ng = (nr >> 4) * 256 + t0 + (nr & 15);
        gload16(WTh + (size_t)ng * 512 + S * 32 + jj * 8, &Bs[(size_t)f * 8]);
    }

    f32x4 acc[RT][5];
    #pragma unroll
    for (int rt = 0; rt < RT; ++rt)
        #pragma unroll
        for (int g = 0; g < 5; ++g) acc[rt][g] = (f32x4)0.f;

    // A depth-1 prefetch ring
    half8 aF[2][RT];
    #pragma unroll
    for (int rt = 0; rt < RT; ++rt)
        aF[0][rt] = LVL1 ? gld8h(h_prev, offA[rt]) : gld8h(h_prev, offA[rt]);

    __syncthreads();                            // B staged (drains gload_lds)

    // ---- 16 K-steps, NO barriers
    #pragma unroll
    for (int S = 0; S < 16; ++S) {
        if (S + 1 < 16) {
            #pragma unroll
            for (int rt = 0; rt < RT; ++rt) {
                if constexpr (LVL1)
                    aF[(S + 1) & 1][rt] = (S + 1 < 8) ? gld8h(h_prev, offA[rt] + (S + 1) * 64u)
                                                      : gld8h(h_prev, offB[rt] + (S + 1 - 8) * 64u);
                else
                    aF[(S + 1) & 1][rt] = gld8h(h_prev, offA[rt] + (S + 1) * 64u);
            }
        }
        #pragma unroll
        for (int g = 0; g < 5; ++g) {
            const int nr = g * 16 + l15;
            const int slot = lg ^ ((nr >> 1) & 3);
            half8 bF = *(const half8*)&Bs[(size_t)(((S * 80 + nr) << 2) + slot) * 8];
            #pragma unroll
            for (int rt = 0; rt < RT; ++rt)
                acc[rt][g] = __builtin_amdgcn_mfma_f32_16x16x32_f16(aF[S & 1][rt], bF, acc[rt][g], 0, 0, 0);
        }
    }

    // ---- fused epilogue. D: col = lane&15, row = (lane>>4)*4 + q
    const int tcol = t0 + l15;
    #pragma unroll
    for (int rt = 0; rt < RT; ++rt) {
        #pragma unroll
        for (int q = 0; q < 4; ++q) {
            int row = rowB + wid * (RT * 16) + rt * 16 + lg * 4 + q;
            int b = row >> ln, j = row & (n - 1);
            int id = ids[b * NODES_ + off + j];
            const float* tp = tab + (size_t)id * 1280 + tcol;
            float c1, c2;
            if constexpr (LVL1) {
                int bb = row >> 7, jj = row & 127;
                c1 = c_prev[(size_t)ids[bb * NODES_ + 2 * jj] * 256 + tcol];
                c2 = c_prev[(size_t)ids[bb * NODES_ + 2 * jj + 1] * 256 + tcol];
            } else {
                const float* cpp = c_prev + (size_t)row * 512 + tcol;
                c1 = cpp[0]; c2 = cpp[256];
            }
            float vi  = sigm(acc[rt][0][q] + tp[0]);
            float vo  = sigm(acc[rt][1][q] + tp[256]);
            float vu  = tanh_f(acc[rt][2][q] + tp[512]);
            float vf0 = sigm(acc[rt][3][q] + tp[768]);
            float vf1 = sigm(acc[rt][4][q] + tp[1024]);
            float c = vi * vu + vf0 * c1 + vf1 * c2;
            size_t ob = (size_t)row * 256 + tcol;
            h_out[ob] = (_Float16)(vo * tanh_f(c));
            c_out[ob] = c;
        }
    }
}

// pred[b] = relu(h_root[b] @ Wl1 + bl1) @ Wl2 + bl2
__global__ void head_kernel(const _Float16* __restrict__ hroot,
    const float* __restrict__ Wl1, const float* __restrict__ bl1,
    const float* __restrict__ Wl2, const float* __restrict__ bl2,
    float* __restrict__ out)
{
    __shared__ float hrow[H_];
    __shared__ float red[256];
    int b = blockIdx.x; int tid = threadIdx.x;
    hrow[tid] = (float)hroot[(size_t)b * H_ + tid];
    __syncthreads();
    float v = 0.f;
    if (tid < 100) {
        float s = bl1[tid];
        for (int k = 0; k < H_; ++k) s = fmaf(hrow[k], Wl1[k * 100 + tid], s);
        v = fmaxf(s, 0.f) * Wl2[tid];
    }
    red[tid] = v;
    __syncthreads();
    for (int s = 128; s > 0; s >>= 1) { if (tid < s) red[tid] += red[tid + s]; __syncthreads(); }
    if (tid == 0) out[b] = red[0] + bl2[0];
}

extern "C" void kernel_launch(void* const* d_in, const int* in_sizes, int n_in,
                              void* d_out, int out_size, void* d_ws, size_t ws_size,
                              hipStream_t stream) {
    const int*   ids    = (const int*)d_in[0];
    const float* emb    = (const float*)d_in[1];
    const float* Wioux  = (const float*)d_in[2];
    const float* bioux  = (const float*)d_in[3];
    const float* Wiouh1 = (const float*)d_in[4];
    const float* biouh1 = (const float*)d_in[5];
    const float* Wiouh2 = (const float*)d_in[6];
    const float* biouh2 = (const float*)d_in[7];
    const float* Wfx    = (const float*)d_in[8];
    const float* bfx    = (const float*)d_in[9];
    const float* Wfh11  = (const float*)d_in[10];
    const float* bfh11  = (const float*)d_in[11];
    const float* Wfh12  = (const float*)d_in[12];
    const float* bfh12  = (const float*)d_in[13];
    const float* Wfh21  = (const float*)d_in[14];
    const float* bfh21  = (const float*)d_in[15];
    const float* Wfh22  = (const float*)d_in[16];
    const float* bfh22  = (const float*)d_in[17];
    const float* Wl1    = (const float*)d_in[18];
    const float* bl1    = (const float*)d_in[19];
    const float* Wl2    = (const float*)d_in[20];
    const float* bl2    = (const float*)d_in[21];
    float* out = (float*)d_out;

    // ws layout (bytes)
    char* wsb = (char*)d_ws;
    _Float16* WTh = (_Float16*)(wsb);                    //  1,310,720
    float*    tab = (float*)(wsb + 1310720);             // 10,485,760
    _Float16* H0h = (_Float16*)(wsb + 11796480);         //  1,048,576
    float*    H0c = (float*)(wsb + 12845056);            //  2,097,152
    _Float16* hA  = (_Float16*)(wsb + 14942208);         //  8,388,608  (lvl 2,4,6,8 out)
    _Float16* hB  = (_Float16*)(wsb + 23330816);         // 16,777,216  (lvl 1,3,5,7 out)
    float*    cA  = (float*)(wsb + 40108032);            // 16,777,216
    float*    cB  = (float*)(wsb + 56885248);            // 33,554,432  -> ends 90,439,680

    build_WTh<<<dim3(2560), 256, 0, stream>>>(WTh, Wiouh1, Wfh11, Wfh21, Wiouh2, Wfh12, Wfh22);
    build_table<<<dim3(32, 20), 256, 0, stream>>>(tab, emb, Wioux, Wfx,
        bioux, biouh1, biouh2, bfx, bfh11, bfh12, bfh21, bfh22);
    build_h0c0<<<dim3(2048), 256, 0, stream>>>(tab, H0h, H0c);

    // level 1: A gathered from id-indexed H0 tables (M = 32768 rows)
    cell8<true, 8><<<dim3(64, 16), 256, 0, stream>>>(WTh, tab, ids, H0h, H0c, hB, cB, 128, 7, 256);

    _Float16 *hp = hB, *hn = hA;
    float    *cp = cB, *cn = cA;
    int off = 384, n = 64, ln = 6;
    for (int lvl = 2; lvl <= 8; ++lvl) {
        int M = B_ * n;
        if (M >= 16384)
            cell8<false, 8><<<dim3(M / 512, 16), 256, 0, stream>>>(WTh, tab, ids, hp, cp, hn, cn, n, ln, off);
        else if (M >= 4096)
            cell8<false, 4><<<dim3(M / 256, 16), 256, 0, stream>>>(WTh, tab, ids, hp, cp, hn, cn, n, ln, off);
        else if (M >= 1024)
            cell8<false, 2><<<dim3(M / 128, 16), 256, 0, stream>>>(WTh, tab, ids, hp, cp, hn, cn, n, ln, off);
        else
            cell8<false, 1><<<dim3(M / 64, 16), 256, 0, stream>>>(WTh, tab, ids, hp, cp, hn, cn, n, ln, off);
        off += n; n >>= 1; --ln;
        _Float16* t1 = hp; hp = hn; hn = t1;
        float*    t2 = cp; cp = cn; cn = t2;
    }

    head_kernel<<<dim3(256), 256, 0, stream>>>(hp, Wl1, bl1, Wl2, bl2, out);
}

// Round 10
// 364.707 us; speedup vs baseline: 2.0800x; 1.2271x over previous
//
#include <hip/hip_runtime.h>
#include <math.h>

#define B_ 256
#define L_ 256
#define V_ 2048
#define DIN_ 128
#define H_ 256
#define NODES_ 511

typedef _Float16 half8 __attribute__((ext_vector_type(8)));
typedef float f32x4 __attribute__((ext_vector_type(4)));

__device__ __forceinline__ float sigm(float x) { return 1.f / (1.f + __expf(-x)); }
__device__ __forceinline__ float tanh_f(float x) {
    float xc = fminf(fmaxf(x, -15.f), 15.f);
    float e = __expf(2.f * xc);
    return (e - 1.f) / (e + 1.f);
}
__device__ __forceinline__ void gload16(const void* g, void* l) {
    __builtin_amdgcn_global_load_lds((const __attribute__((address_space(1))) unsigned int*)g,
                                     (__attribute__((address_space(3))) unsigned int*)l, 16, 0, 0);
}
__device__ __forceinline__ half8 gld8h(const _Float16* base, unsigned byteOff) {
    return *(const half8*)((const char*)base + byteOff);
}

// WTh[n][k] fp16: h-part weights only. n = g*256+t (g:0=i,1=o,2=u,3=f0,4=f1), k:[0,256)=h1,[256,512)=h2
__global__ void build_WTh(_Float16* __restrict__ WTh,
    const float* __restrict__ Wiouh1, const float* __restrict__ Wfh11, const float* __restrict__ Wfh21,
    const float* __restrict__ Wiouh2, const float* __restrict__ Wfh12, const float* __restrict__ Wfh22)
{
    int e = blockIdx.x * 256 + threadIdx.x;   // < 1280*512
    int nn = e >> 9, k = e & 511;
    int g = nn >> 8, t = nn & 255;
    float v;
    if (k < 256) {
        v = (g < 3) ? Wiouh1[k * 768 + nn] : ((g == 3) ? Wfh11[k * 256 + t] : Wfh21[k * 256 + t]);
    } else {
        int kp = k - 256;
        v = (g < 3) ? Wiouh2[kp * 768 + nn] : ((g == 3) ? Wfh12[kp * 256 + t] : Wfh22[kp * 256 + t]);
    }
    WTh[e] = (_Float16)v;
}

// tab[id][col] f32 = emb(id,:) @ Wx_fused(:,col) + bias_total(col); emb row 0 zeroed.
__global__ __launch_bounds__(256) void build_table(float* __restrict__ tab, const float* __restrict__ emb,
    const float* __restrict__ Wioux, const float* __restrict__ Wfx,
    const float* __restrict__ bioux, const float* __restrict__ biouh1, const float* __restrict__ biouh2,
    const float* __restrict__ bfx, const float* __restrict__ bfh11, const float* __restrict__ bfh12,
    const float* __restrict__ bfh21, const float* __restrict__ bfh22)
{
    __shared__ float As[64][33];
    __shared__ float Ws[32][65];
    const int tid = threadIdx.x, tx = tid & 15, ty = tid >> 4;
    const int i0 = blockIdx.x * 64, c0 = blockIdx.y * 64;
    const int g = c0 >> 8;
    float acc[4][4];
    #pragma unroll
    for (int i = 0; i < 4; ++i)
        #pragma unroll
        for (int j = 0; j < 4; ++j) acc[i][j] = 0.f;

    for (int k0 = 0; k0 < 128; k0 += 32) {
        #pragma unroll
        for (int it = 0; it < 2; ++it) {
            int f = tid + it * 256;
            int row = f >> 3, kk = (f & 7) * 4;
            int gr = i0 + row;
            float4 av = (gr == 0) ? make_float4(0.f, 0.f, 0.f, 0.f)
                                  : *(const float4*)(emb + (size_t)gr * 128 + k0 + kk);
            As[row][kk] = av.x; As[row][kk + 1] = av.y; As[row][kk + 2] = av.z; As[row][kk + 3] = av.w;
            int k = f >> 4, cc = (f & 15) * 4;
            int col = c0 + cc;
            float4 wv = (g < 3) ? *(const float4*)(Wioux + (size_t)(k0 + k) * 768 + col)
                                : *(const float4*)(Wfx + (size_t)(k0 + k) * 256 + (col & 255));
            Ws[k][cc] = wv.x; Ws[k][cc + 1] = wv.y; Ws[k][cc + 2] = wv.z; Ws[k][cc + 3] = wv.w;
        }
        __syncthreads();
        #pragma unroll 8
        for (int k = 0; k < 32; ++k) {
            float a[4], w[4];
            #pragma unroll
            for (int i = 0; i < 4; ++i) a[i] = As[ty * 4 + i][k];
            #pragma unroll
            for (int j = 0; j < 4; ++j) w[j] = Ws[k][tx * 4 + j];
            #pragma unroll
            for (int i = 0; i < 4; ++i)
                #pragma unroll
                for (int j = 0; j < 4; ++j) acc[i][j] = fmaf(a[i], w[j], acc[i][j]);
        }
        __syncthreads();
    }
    #pragma unroll
    for (int j = 0; j < 4; ++j) {
        int col = c0 + tx * 4 + j; int t = col & 255;
        float bs = (g < 3) ? (bioux[col] + biouh1[col] + biouh2[col])
                 : (g == 3) ? (bfx[t] + bfh11[t] + bfh12[t])
                            : (bfx[t] + bfh21[t] + bfh22[t]);
        #pragma unroll
        for (int i = 0; i < 4; ++i)
            tab[(size_t)(i0 + ty * 4 + i) * 1280 + col] = acc[i][j] + bs;
    }
}

// Level-0 result depends only on token id: H0h/H0c[id][t]
__global__ void build_h0c0(const float* __restrict__ tab, _Float16* __restrict__ H0h, float* __restrict__ H0c) {
    int id = blockIdx.x, t = threadIdx.x;
    const float* tp = tab + (size_t)id * 1280 + t;
    float vi = sigm(tp[0]), vo = sigm(tp[256]), vu = tanh_f(tp[512]);
    float c = vi * vu;
    H0h[id * 256 + t] = (_Float16)(vo * tanh_f(c));
    H0c[id * 256 + t] = c;
}

// Tree-level cell v9: COLUMN-split waves for full-line stores.
// Block = BM(=RT*16) rows x 64 t-cols x 5 gates; wave w owns t-cols [C0+w*16, +16), all rows.
// B: 320 n-rows x K=128 phase staged in 80KB LDS (conflict-free swizzle, R7-verified), 4 phases.
// A: per-lane direct global loads (identical across waves -> L1 dedup), depth-2 ring.
// Epilogue: results routed through LDS, then full-line coalesced global stores.
template<bool LVL1, int RT>
__global__ __launch_bounds__(256, 2) void cell9(
    const _Float16* __restrict__ WTh, const float* __restrict__ tab,
    const int* __restrict__ ids,
    const _Float16* __restrict__ h_prev, const float* __restrict__ c_prev,
    _Float16* __restrict__ h_out, float* __restrict__ c_out,
    int n, int ln, int off)
{
    constexpr int BM = RT * 16;
    __shared__ __align__(16) _Float16 Bs[40960];       // 80 KB = 5120 slots of 16B
    const int tid = threadIdx.x, lane = tid & 63, wid = tid >> 6;
    const int l15 = lane & 15, lg = lane >> 4;
    const int rowB = blockIdx.x * BM;
    const int C0 = blockIdx.y * 64;

    // ---- A byte-offsets per row-frag (bases uniform)
    unsigned offA[RT];
    unsigned offB[LVL1 ? RT : 1];
    #pragma unroll
    for (int rt = 0; rt < RT; ++rt) {
        int row = rowB + rt * 16 + l15;
        if constexpr (LVL1) {
            int b = row >> 7, j = row & 127;
            offA[rt] = (unsigned)ids[b * NODES_ + 2 * j] * 512u + lg * 16u;      // H0h row = 512B
            offB[rt] = (unsigned)ids[b * NODES_ + 2 * j + 1] * 512u + lg * 16u;
        } else {
            offA[rt] = (unsigned)row * 1024u + lg * 16u;                          // [h1|h2] = 1024B
        }
    }

    // ---- B staging offsets (hoisted; +256B per phase). Slot f = tid + i*256 (5120 total).
    // f -> S'(k-step in phase) = f/1280; sr = (f%1280)>>2 = W*80+nr; jj' = f&3.
    // Slot holds global k-seg jj = jj' ^ ((nr>>1)&3)  [proven conflict-free on read].
    unsigned boff[20];
    #pragma unroll
    for (int i = 0; i < 20; ++i) {
        int f = tid + i * 256;
        int S1 = f / 1280, rem = f - S1 * 1280;
        int sr = rem >> 2, jjp = rem & 3;
        int W = sr / 80, nr = sr - W * 80;
        int jj = jjp ^ ((nr >> 1) & 3);
        int ncol = (nr >> 4) * 256 + C0 + W * 16 + (nr & 15);
        boff[i] = (unsigned)((ncol * 512 + S1 * 32 + jj * 8) * 2);
    }
    // stage phase 0
    #pragma unroll
    for (int i = 0; i < 20; ++i)
        gload16((const char*)WTh + boff[i], &Bs[(size_t)(tid + i * 256) * 8]);

    f32x4 acc[RT][5];
    #pragma unroll
    for (int rt = 0; rt < RT; ++rt)
        #pragma unroll
        for (int g = 0; g < 5; ++g) acc[rt][g] = (f32x4)0.f;

    // A depth-2 prefetch ring
    half8 aF[3][RT];
    #pragma unroll
    for (int rt = 0; rt < RT; ++rt) aF[0][rt] = gld8h(h_prev, offA[rt]);
    #pragma unroll
    for (int rt = 0; rt < RT; ++rt)
        aF[1][rt] = LVL1 ? gld8h(h_prev, offA[rt] + 64u) : gld8h(h_prev, offA[rt] + 64u);

    __syncthreads();                            // phase-0 B staged

    #pragma unroll
    for (int p = 0; p < 4; ++p) {
        #pragma unroll
        for (int sl = 0; sl < 4; ++sl) {
            const int S = p * 4 + sl;
            const int pf = S + 2;
            if (pf < 16) {
                #pragma unroll
                for (int rt = 0; rt < RT; ++rt) {
                    if constexpr (LVL1)
                        aF[pf % 3][rt] = (pf < 8) ? gld8h(h_prev, offA[rt] + pf * 64u)
                                                  : gld8h(h_prev, offB[rt] + (pf - 8) * 64u);
                    else
                        aF[pf % 3][rt] = gld8h(h_prev, offA[rt] + pf * 64u);
                }
            }
            #pragma unroll
            for (int g = 0; g < 5; ++g) {
                const int nr = g * 16 + l15;
                const int slot = lg ^ ((nr >> 1) & 3);
                half8 bF = *(const half8*)&Bs[(size_t)((sl * 1280 + wid * 320 + nr * 4 + slot)) * 8];
                #pragma unroll
                for (int rt = 0; rt < RT; ++rt)
                    acc[rt][g] = __builtin_amdgcn_mfma_f32_16x16x32_f16(aF[S % 3][rt], bF, acc[rt][g], 0, 0, 0);
            }
        }
        if (p < 3) {
            __syncthreads();                    // phase-p reads done
            #pragma unroll
            for (int i = 0; i < 20; ++i)
                gload16((const char*)WTh + boff[i] + (p + 1) * 256u, &Bs[(size_t)(tid + i * 256) * 8]);
            __syncthreads();                    // phase-(p+1) staged
        }
    }
    __syncthreads();                            // last-phase reads done; reuse Bs for epilogue

    // ---- epilogue: compute gates, stash in LDS, then full-line coalesced stores
    _Float16* h_lds = (_Float16*)Bs;                    // [BM][72] halves (144B rows, 16B-aligned)
    float*    c_lds = (float*)((char*)Bs + 9216);       // [BM][68] f32    (272B rows, 16B-aligned)
    const int tcol = C0 + wid * 16 + l15;
    #pragma unroll
    for (int rt = 0; rt < RT; ++rt) {
        #pragma unroll
        for (int q = 0; q < 4; ++q) {
            int rl = rt * 16 + lg * 4 + q;
            int row = rowB + rl;
            int b = row >> ln, j = row & (n - 1);
            int id = ids[b * NODES_ + off + j];
            const float* tp = tab + (size_t)id * 1280 + tcol;
            float c1, c2;
            if constexpr (LVL1) {
                int bb = row >> 7, jj = row & 127;
                c1 = c_prev[(size_t)ids[bb * NODES_ + 2 * jj] * 256 + tcol];
                c2 = c_prev[(size_t)ids[bb * NODES_ + 2 * jj + 1] * 256 + tcol];
            } else {
                const float* cpp = c_prev + (size_t)row * 512 + tcol;
                c1 = cpp[0]; c2 = cpp[256];
            }
            float vi  = sigm(acc[rt][0][q] + tp[0]);
            float vo  = sigm(acc[rt][1][q] + tp[256]);
            float vu  = tanh_f(acc[rt][2][q] + tp[512]);
            float vf0 = sigm(acc[rt][3][q] + tp[768]);
            float vf1 = sigm(acc[rt][4][q] + tp[1024]);
            float c = vi * vu + vf0 * c1 + vf1 * c2;
            h_lds[rl * 72 + wid * 16 + l15] = (_Float16)(vo * tanh_f(c));
            c_lds[rl * 68 + wid * 16 + l15] = c;
        }
    }
    __syncthreads();
    // h: BM rows x 128B (8 x 16B); 8 threads per row -> full line
    for (int i = tid; i < BM * 8; i += 256) {
        int row = i >> 3, seg = i & 7;
        *(half8*)(h_out + (size_t)(rowB + row) * 256 + C0 + seg * 8) =
            *(const half8*)&h_lds[row * 72 + seg * 8];
    }
    // c: BM rows x 256B (16 x 16B)
    for (int i = tid; i < BM * 16; i += 256) {
        int row = i >> 4, seg = i & 15;
        *(f32x4*)(c_out + (size_t)(rowB + row) * 256 + C0 + seg * 4) =
            *(const f32x4*)&c_lds[row * 68 + seg * 4];
    }
}

// pred[b] = relu(h_root[b] @ Wl1 + bl1) @ Wl2 + bl2
__global__ void head_kernel(const _Float16* __restrict__ hroot,
    const float* __restrict__ Wl1, const float* __restrict__ bl1,
    const float* __restrict__ Wl2, const float* __restrict__ bl2,
    float* __restrict__ out)
{
    __shared__ float hrow[H_];
    __shared__ float red[256];
    int b = blockIdx.x; int tid = threadIdx.x;
    hrow[tid] = (float)hroot[(size_t)b * H_ + tid];
    __syncthreads();
    float v = 0.f;
    if (tid < 100) {
        float s = bl1[tid];
        for (int k = 0; k < H_; ++k) s = fmaf(hrow[k], Wl1[k * 100 + tid], s);
        v = fmaxf(s, 0.f) * Wl2[tid];
    }
    red[tid] = v;
    __syncthreads();
    for (int s = 128; s > 0; s >>= 1) { if (tid < s) red[tid] += red[tid + s]; __syncthreads(); }
    if (tid == 0) out[b] = red[0] + bl2[0];
}

extern "C" void kernel_launch(void* const* d_in, const int* in_sizes, int n_in,
                              void* d_out, int out_size, void* d_ws, size_t ws_size,
                              hipStream_t stream) {
    const int*   ids    = (const int*)d_in[0];
    const float* emb    = (const float*)d_in[1];
    const float* Wioux  = (const float*)d_in[2];
    const float* bioux  = (const float*)d_in[3];
    const float* Wiouh1 = (const float*)d_in[4];
    const float* biouh1 = (const float*)d_in[5];
    const float* Wiouh2 = (const float*)d_in[6];
    const float* biouh2 = (const float*)d_in[7];
    const float* Wfx    = (const float*)d_in[8];
    const float* bfx    = (const float*)d_in[9];
    const float* Wfh11  = (const float*)d_in[10];
    const float* bfh11  = (const float*)d_in[11];
    const float* Wfh12  = (const float*)d_in[12];
    const float* bfh12  = (const float*)d_in[13];
    const float* Wfh21  = (const float*)d_in[14];
    const float* bfh21  = (const float*)d_in[15];
    const float* Wfh22  = (const float*)d_in[16];
    const float* bfh22  = (const float*)d_in[17];
    const float* Wl1    = (const float*)d_in[18];
    const float* bl1    = (const float*)d_in[19];
    const float* Wl2    = (const float*)d_in[20];
    const float* bl2    = (const float*)d_in[21];
    float* out = (float*)d_out;

    // ws layout (bytes)
    char* wsb = (char*)d_ws;
    _Float16* WTh = (_Float16*)(wsb);                    //  1,310,720
    float*    tab = (float*)(wsb + 1310720);             // 10,485,760
    _Float16* H0h = (_Float16*)(wsb + 11796480);         //  1,048,576
    float*    H0c = (float*)(wsb + 12845056);            //  2,097,152
    _Float16* hA  = (_Float16*)(wsb + 14942208);         //  8,388,608  (lvl 2,4,6,8 out)
    _Float16* hB  = (_Float16*)(wsb + 23330816);         // 16,777,216  (lvl 1,3,5,7 out)
    float*    cA  = (float*)(wsb + 40108032);            // 16,777,216
    float*    cB  = (float*)(wsb + 56885248);            // 33,554,432  -> ends 90,439,680

    build_WTh<<<dim3(2560), 256, 0, stream>>>(WTh, Wiouh1, Wfh11, Wfh21, Wiouh2, Wfh12, Wfh22);
    build_table<<<dim3(32, 20), 256, 0, stream>>>(tab, emb, Wioux, Wfx,
        bioux, biouh1, biouh2, bfx, bfh11, bfh12, bfh21, bfh22);
    build_h0c0<<<dim3(2048), 256, 0, stream>>>(tab, H0h, H0c);

    // level 1 (M = 32768 rows)
    cell9<true, 4><<<dim3(512, 4), 256, 0, stream>>>(WTh, tab, ids, H0h, H0c, hB, cB, 128, 7, 256);

    _Float16 *hp = hB, *hn = hA;
    float    *cp = cB, *cn = cA;
    int off = 384, n = 64, ln = 6;
    for (int lvl = 2; lvl <= 8; ++lvl) {
        int M = B_ * n;
        if (M >= 4096)
            cell9<false, 4><<<dim3(M / 64, 4), 256, 0, stream>>>(WTh, tab, ids, hp, cp, hn, cn, n, ln, off);
        else if (M >= 1024)
            cell9<false, 2><<<dim3(M / 32, 4), 256, 0, stream>>>(WTh, tab, ids, hp, cp, hn, cn, n, ln, off);
        else
            cell9<false, 1><<<dim3(M / 16, 4), 256, 0, stream>>>(WTh, tab, ids, hp, cp, hn, cn, n, ln, off);
        off += n; n >>= 1; --ln;
        _Float16* t1 = hp; hp = hn; hn = t1;
        float*    t2 = cp; cp = cn; cn = t2;
    }

    head_kernel<<<dim3(256), 256, 0, stream>>>(hp, Wl1, bl1, Wl2, bl2, out);
}

// Round 11
// 305.373 us; speedup vs baseline: 2.4842x; 1.1943x over previous
//
#include <hip/hip_runtime.h>
#include <math.h>

#define B_ 256
#define L_ 256
#define V_ 2048
#define DIN_ 128
#define H_ 256
#define NODES_ 511

typedef _Float16 half8 __attribute__((ext_vector_type(8)));
typedef float f32x4 __attribute__((ext_vector_type(4)));

__device__ __forceinline__ float sigm(float x) { return 1.f / (1.f + __expf(-x)); }
__device__ __forceinline__ float tanh_f(float x) {
    float xc = fminf(fmaxf(x, -15.f), 15.f);
    float e = __expf(2.f * xc);
    return (e - 1.f) / (e + 1.f);
}
__device__ __forceinline__ void gload16(const void* g, void* l) {
    __builtin_amdgcn_global_load_lds((const __attribute__((address_space(1))) unsigned int*)g,
                                     (__attribute__((address_space(3))) unsigned int*)l, 16, 0, 0);
}

// WTh[n][k] fp16: h-part weights. n = g*256+t (g:0=i,1=o,2=u,3=f0,4=f1), k:[0,256)=h1,[256,512)=h2
__global__ void build_WTh(_Float16* __restrict__ WTh,
    const float* __restrict__ Wiouh1, const float* __restrict__ Wfh11, const float* __restrict__ Wfh21,
    const float* __restrict__ Wiouh2, const float* __restrict__ Wfh12, const float* __restrict__ Wfh22)
{
    int e = blockIdx.x * 256 + threadIdx.x;   // < 1280*512
    int nn = e >> 9, k = e & 511;
    int g = nn >> 8, t = nn & 255;
    float v;
    if (k < 256) {
        v = (g < 3) ? Wiouh1[k * 768 + nn] : ((g == 3) ? Wfh11[k * 256 + t] : Wfh21[k * 256 + t]);
    } else {
        int kp = k - 256;
        v = (g < 3) ? Wiouh2[kp * 768 + nn] : ((g == 3) ? Wfh12[kp * 256 + t] : Wfh22[kp * 256 + t]);
    }
    WTh[e] = (_Float16)v;
}

// tabP: panelized x-part+bias table. tabP[((p*2048 + id)*5 + g)*16 + q], col = g*256 + p*16 + q.
__global__ __launch_bounds__(256) void build_tabP(float* __restrict__ tabP, const float* __restrict__ emb,
    const float* __restrict__ Wioux, const float* __restrict__ Wfx,
    const float* __restrict__ bioux, const float* __restrict__ biouh1, const float* __restrict__ biouh2,
    const float* __restrict__ bfx, const float* __restrict__ bfh11, const float* __restrict__ bfh12,
    const float* __restrict__ bfh21, const float* __restrict__ bfh22)
{
    __shared__ float As[64][33];
    __shared__ float Ws[32][65];
    const int tid = threadIdx.x, tx = tid & 15, ty = tid >> 4;
    const int i0 = blockIdx.x * 64, c0 = blockIdx.y * 64;
    const int g = c0 >> 8;
    float acc[4][4];
    #pragma unroll
    for (int i = 0; i < 4; ++i)
        #pragma unroll
        for (int j = 0; j < 4; ++j) acc[i][j] = 0.f;

    for (int k0 = 0; k0 < 128; k0 += 32) {
        #pragma unroll
        for (int it = 0; it < 2; ++it) {
            int f = tid + it * 256;
            int row = f >> 3, kk = (f & 7) * 4;
            int gr = i0 + row;
            float4 av = (gr == 0) ? make_float4(0.f, 0.f, 0.f, 0.f)
                                  : *(const float4*)(emb + (size_t)gr * 128 + k0 + kk);
            As[row][kk] = av.x; As[row][kk + 1] = av.y; As[row][kk + 2] = av.z; As[row][kk + 3] = av.w;
            int k = f >> 4, cc = (f & 15) * 4;
            int col = c0 + cc;
            float4 wv = (g < 3) ? *(const float4*)(Wioux + (size_t)(k0 + k) * 768 + col)
                                : *(const float4*)(Wfx + (size_t)(k0 + k) * 256 + (col & 255));
            Ws[k][cc] = wv.x; Ws[k][cc + 1] = wv.y; Ws[k][cc + 2] = wv.z; Ws[k][cc + 3] = wv.w;
        }
        __syncthreads();
        #pragma unroll 8
        for (int k = 0; k < 32; ++k) {
            float a[4], w[4];
            #pragma unroll
            for (int i = 0; i < 4; ++i) a[i] = As[ty * 4 + i][k];
            #pragma unroll
            for (int j = 0; j < 4; ++j) w[j] = Ws[k][tx * 4 + j];
            #pragma unroll
            for (int i = 0; i < 4; ++i)
                #pragma unroll
                for (int j = 0; j < 4; ++j) acc[i][j] = fmaf(a[i], w[j], acc[i][j]);
        }
        __syncthreads();
    }
    #pragma unroll
    for (int j = 0; j < 4; ++j) {
        int col = c0 + tx * 4 + j; int t = col & 255;
        int p = t >> 4, q = t & 15;
        float bs = (g < 3) ? (bioux[col] + biouh1[col] + biouh2[col])
                 : (g == 3) ? (bfx[t] + bfh11[t] + bfh12[t])
                            : (bfx[t] + bfh21[t] + bfh22[t]);
        #pragma unroll
        for (int i = 0; i < 4; ++i) {
            int id = i0 + ty * 4 + i;
            tabP[((size_t)(p * 2048 + id) * 5 + g) * 16 + q] = acc[i][j] + bs;
        }
    }
}

// Level-0 tables in PANEL form: H0hP/H0cP[p][id][16]
__global__ void build_h0c0P(const float* __restrict__ tabP, _Float16* __restrict__ H0hP, float* __restrict__ H0cP) {
    int id = blockIdx.x, t = threadIdx.x;
    int p = t >> 4, q = t & 15;
    size_t base = (size_t)(p * 2048 + id) * 80 + q;
    float vi = sigm(tabP[base]), vo = sigm(tabP[base + 16]), vu = tanh_f(tabP[base + 32]);
    float c = vi * vu;
    H0hP[(size_t)p * 32768 + id * 16 + q] = (_Float16)(vo * tanh_f(c));
    H0cP[(size_t)p * 32768 + id * 16 + q] = c;
}

// Tree-level cell vE: panel-major I/O, full-K B in LDS (80KB, 0-conflict R8 layout),
// zero K-loop barriers, row-split waves (RT frags each), XCD-chunked 1-D grid swizzle.
// Panels: h[p][row][16] fp16 (32B rows), c[p][row][16] f32 (64B rows), p = tcol/16.
template<bool LVL1, int RT>
__global__ __launch_bounds__(256, 2) void cellE(
    const _Float16* __restrict__ WTh, const float* __restrict__ tabP,
    const int* __restrict__ ids,
    const _Float16* __restrict__ hPrev, const float* __restrict__ cPrev,
    _Float16* __restrict__ hOut, float* __restrict__ cOut,
    int M, int Mprev, int n, int ln, int off, int nb)
{
    constexpr int BM = RT * 64;
    __shared__ __align__(16) _Float16 Bs[40960];        // 80 KB
    const int tid = threadIdx.x, lane = tid & 63, wid = tid >> 6;
    const int l15 = lane & 15, lg = lane >> 4;
    // XCD-chunked swizzle: consecutive hw-dispatch ids (same XCD) share the same row-group x
    int sw = (blockIdx.x & 7) * (nb >> 3) + (blockIdx.x >> 3);
    const int y = sw & 15;                               // t-col panel
    const int x = sw >> 4;
    const int rowB = x * BM;
    const unsigned PBH = (unsigned)Mprev * 32u;          // h panel stride (bytes)

    // ---- A byte-bases per row-frag (gather rows use l15; seg lg)
    unsigned baseA[RT], baseB[RT];
    #pragma unroll
    for (int rt = 0; rt < RT; ++rt) {
        int r = rowB + wid * (RT * 16) + rt * 16 + l15;
        if constexpr (LVL1) {
            int b = r >> 7, j = r & 127;
            baseA[rt] = (unsigned)ids[b * NODES_ + 2 * j] * 32u + (lg & 1) * 16u;
            baseB[rt] = (unsigned)ids[b * NODES_ + 2 * j + 1] * 32u + (lg & 1) * 16u;
        } else {
            baseA[rt] = (unsigned)(2 * r) * 32u + (lg & 1) * 16u;
            baseB[rt] = baseA[rt] + 32u;
        }
    }

    // ---- stage full-K B slice (R8-verbatim layout: 0 bank conflicts)
    unsigned boff[20];
    #pragma unroll
    for (int i = 0; i < 20; ++i) {
        int f = tid + i * 256;
        int srow = f >> 2, jjp = f & 3;
        int S = srow / 80, nr = srow - S * 80;
        int jj = jjp ^ ((nr >> 1) & 3);
        int ng = (nr >> 4) * 256 + y * 16 + (nr & 15);
        boff[i] = (unsigned)((ng * 512 + S * 32 + jj * 8) * 2);
    }
    #pragma unroll
    for (int i = 0; i < 20; ++i)
        gload16((const char*)WTh + boff[i], &Bs[(size_t)(tid + i * 256) * 8]);

    f32x4 acc[RT][5];
    #pragma unroll
    for (int rt = 0; rt < RT; ++rt)
        #pragma unroll
        for (int g = 0; g < 5; ++g) acc[rt][g] = (f32x4)0.f;

    // A prefetch ring depth 2 (ring of 3). Panel addressing:
    // step S: k = S*32 + lg*8; half = S>=8; p = (S&7)*2 + (lg>>1); byte = p*PBH + base
    half8 aF[3][RT];
    #pragma unroll
    for (int rt = 0; rt < RT; ++rt)
        aF[0][rt] = *(const half8*)((const char*)hPrev + (unsigned)(lg >> 1) * PBH + baseA[rt]);
    #pragma unroll
    for (int rt = 0; rt < RT; ++rt)
        aF[1][rt] = *(const half8*)((const char*)hPrev + (unsigned)(2 + (lg >> 1)) * PBH + baseA[rt]);

    __syncthreads();                                     // B staged

    // ---- 16 K-steps, NO barriers
    #pragma unroll
    for (int S = 0; S < 16; ++S) {
        const int pf = S + 2;
        if (pf < 16) {
            const unsigned po = (unsigned)(((pf & 7) * 2) + (lg >> 1)) * PBH;
            #pragma unroll
            for (int rt = 0; rt < RT; ++rt)
                aF[pf % 3][rt] = *(const half8*)((const char*)hPrev + po +
                                                 (pf < 8 ? baseA[rt] : baseB[rt]));
        }
        #pragma unroll
        for (int g = 0; g < 5; ++g) {
            const int nr = g * 16 + l15;
            const int slot = lg ^ ((nr >> 1) & 3);
            half8 bF = *(const half8*)&Bs[(size_t)(((S * 80 + nr) << 2) + slot) * 8];
            #pragma unroll
            for (int rt = 0; rt < RT; ++rt)
                acc[rt][g] = __builtin_amdgcn_mfma_f32_16x16x32_f16(aF[S % 3][rt], bF, acc[rt][g], 0, 0, 0);
        }
    }

    __syncthreads();                                     // B reads done; reuse Bs for epilogue
    _Float16* h_lds = (_Float16*)Bs;                     // [BM][16] halves
    float*    c_lds = (float*)((char*)Bs + BM * 32);     // [BM][16] f32

    // ---- fused epilogue. D: col = l15, row = lg*4 + q
    #pragma unroll
    for (int rt = 0; rt < RT; ++rt) {
        #pragma unroll
        for (int q = 0; q < 4; ++q) {
            int rl = wid * (RT * 16) + rt * 16 + lg * 4 + q;
            int row = rowB + rl;
            int b = row >> ln, j = row & (n - 1);
            int id = ids[b * NODES_ + off + j];
            const float* tp = tabP + ((size_t)(y * 2048 + id) * 5) * 16 + l15;
            float c1, c2;
            if constexpr (LVL1) {
                int bb = row >> 7, jj = row & 127;
                int idA = ids[bb * NODES_ + 2 * jj];
                int idB = ids[bb * NODES_ + 2 * jj + 1];
                c1 = cPrev[(size_t)y * 32768 + idA * 16 + l15];
                c2 = cPrev[(size_t)y * 32768 + idB * 16 + l15];
            } else {
                const float* cpp = cPrev + (size_t)y * ((size_t)Mprev * 16) + (size_t)(2 * row) * 16 + l15;
                c1 = cpp[0]; c2 = cpp[16];
            }
            float vi  = sigm(acc[rt][0][q] + tp[0]);
            float vo  = sigm(acc[rt][1][q] + tp[16]);
            float vu  = tanh_f(acc[rt][2][q] + tp[32]);
            float vf0 = sigm(acc[rt][3][q] + tp[48]);
            float vf1 = sigm(acc[rt][4][q] + tp[64]);
            float c = vi * vu + vf0 * c1 + vf1 * c2;
            h_lds[rl * 16 + l15] = (_Float16)(vo * tanh_f(c));
            c_lds[rl * 16 + l15] = c;
        }
    }
    __syncthreads();
    // dense panel stores: h = BM*32B contiguous, c = BM*64B contiguous
    const size_t hP = (size_t)y * ((size_t)M * 16);
    for (int i = tid; i < BM * 2; i += 256)
        *(half8*)(hOut + hP + (size_t)(rowB * 16) + i * 8) = *(const half8*)&h_lds[i * 8];
    for (int i = tid; i < BM * 4; i += 256)
        *(f32x4*)(cOut + hP + (size_t)(rowB * 16) + i * 4) = *(const f32x4*)&c_lds[i * 4];
}

// pred[b] = relu(h_root[b] @ Wl1 + bl1) @ Wl2 + bl2; hroot is panel-major with M=256
__global__ void head_kernel(const _Float16* __restrict__ hroot,
    const float* __restrict__ Wl1, const float* __restrict__ bl1,
    const float* __restrict__ Wl2, const float* __restrict__ bl2,
    float* __restrict__ out)
{
    __shared__ float hrow[H_];
    __shared__ float red[256];
    int b = blockIdx.x; int tid = threadIdx.x;
    hrow[tid] = (float)hroot[(size_t)(tid >> 4) * 4096 + b * 16 + (tid & 15)];
    __syncthreads();
    float v = 0.f;
    if (tid < 100) {
        float s = bl1[tid];
        for (int k = 0; k < H_; ++k) s = fmaf(hrow[k], Wl1[k * 100 + tid], s);
        v = fmaxf(s, 0.f) * Wl2[tid];
    }
    red[tid] = v;
    __syncthreads();
    for (int s = 128; s > 0; s >>= 1) { if (tid < s) red[tid] += red[tid + s]; __syncthreads(); }
    if (tid == 0) out[b] = red[0] + bl2[0];
}

extern "C" void kernel_launch(void* const* d_in, const int* in_sizes, int n_in,
                              void* d_out, int out_size, void* d_ws, size_t ws_size,
                              hipStream_t stream) {
    const int*   ids    = (const int*)d_in[0];
    const float* emb    = (const float*)d_in[1];
    const float* Wioux  = (const float*)d_in[2];
    const float* bioux  = (const float*)d_in[3];
    const float* Wiouh1 = (const float*)d_in[4];
    const float* biouh1 = (const float*)d_in[5];
    const float* Wiouh2 = (const float*)d_in[6];
    const float* biouh2 = (const float*)d_in[7];
    const float* Wfx    = (const float*)d_in[8];
    const float* bfx    = (const float*)d_in[9];
    const float* Wfh11  = (const float*)d_in[10];
    const float* bfh11  = (const float*)d_in[11];
    const float* Wfh12  = (const float*)d_in[12];
    const float* bfh12  = (const float*)d_in[13];
    const float* Wfh21  = (const float*)d_in[14];
    const float* bfh21  = (const float*)d_in[15];
    const float* Wfh22  = (const float*)d_in[16];
    const float* bfh22  = (const float*)d_in[17];
    const float* Wl1    = (const float*)d_in[18];
    const float* bl1    = (const float*)d_in[19];
    const float* Wl2    = (const float*)d_in[20];
    const float* bl2    = (const float*)d_in[21];
    float* out = (float*)d_out;

    // ws layout (bytes)
    char* wsb = (char*)d_ws;
    _Float16* WTh  = (_Float16*)(wsb);                   //  1,310,720
    float*    tabP = (float*)(wsb + 1310720);            // 10,485,760
    _Float16* H0hP = (_Float16*)(wsb + 11796480);        //  1,048,576
    float*    H0cP = (float*)(wsb + 12845056);           //  2,097,152
    _Float16* hA   = (_Float16*)(wsb + 14942208);        //  8,388,608  (lvl 2,4,6,8 out)
    _Float16* hB   = (_Float16*)(wsb + 23330816);        // 16,777,216  (lvl 1,3,5,7 out)
    float*    cA   = (float*)(wsb + 40108032);           // 16,777,216
    float*    cB   = (float*)(wsb + 56885248);           // 33,554,432

    build_WTh<<<dim3(2560), 256, 0, stream>>>(WTh, Wiouh1, Wfh11, Wfh21, Wiouh2, Wfh12, Wfh22);
    build_tabP<<<dim3(32, 20), 256, 0, stream>>>(tabP, emb, Wioux, Wfx,
        bioux, biouh1, biouh2, bfx, bfh11, bfh12, bfh21, bfh22);
    build_h0c0P<<<dim3(2048), 256, 0, stream>>>(tabP, H0hP, H0cP);

    // level 1: M=32768, tables as prev (Mprev=2048)
    cellE<true, 4><<<dim3(2048), 256, 0, stream>>>(WTh, tabP, ids, H0hP, H0cP, hB, cB,
                                                   32768, 2048, 128, 7, 256, 2048);

    _Float16 *hp = hB, *hn = hA;
    float    *cp = cB, *cn = cA;
    int off = 384, n = 64, ln = 6, M = 16384;
    for (int lvl = 2; lvl <= 8; ++lvl) {
        int Mprev = 2 * M;
        if (M >= 4096) {
            int nb = (M / 256) * 16;
            cellE<false, 4><<<dim3(nb), 256, 0, stream>>>(WTh, tabP, ids, hp, cp, hn, cn, M, Mprev, n, ln, off, nb);
        } else if (M >= 2048) {
            int nb = (M / 128) * 16;
            cellE<false, 2><<<dim3(nb), 256, 0, stream>>>(WTh, tabP, ids, hp, cp, hn, cn, M, Mprev, n, ln, off, nb);
        } else {
            int nb = (M / 64) * 16;
            cellE<false, 1><<<dim3(nb), 256, 0, stream>>>(WTh, tabP, ids, hp, cp, hn, cn, M, Mprev, n, ln, off, nb);
        }
        off += n; n >>= 1; --ln; M >>= 1;
        _Float16* t1 = hp; hp = hn; hn = t1;
        float*    t2 = cp; cp = cn; cn = t2;
    }

    head_kernel<<<dim3(256), 256, 0, stream>>>(hp, Wl1, bl1, Wl2, bl2, out);
}

// Round 12
// 289.700 us; speedup vs baseline: 2.6186x; 1.0541x over previous
//
#include <hip/hip_runtime.h>
#include <math.h>

#define B_ 256
#define L_ 256
#define V_ 2048
#define DIN_ 128
#define H_ 256
#define NODES_ 511

typedef _Float16 half8 __attribute__((ext_vector_type(8)));
typedef float f32x4 __attribute__((ext_vector_type(4)));

__device__ __forceinline__ float sigm(float x) { return 1.f / (1.f + __expf(-x)); }
__device__ __forceinline__ float tanh_f(float x) {
    float xc = fminf(fmaxf(x, -15.f), 15.f);
    float e = __expf(2.f * xc);
    return (e - 1.f) / (e + 1.f);
}
__device__ __forceinline__ void gload16(const void* g, void* l) {
    __builtin_amdgcn_global_load_lds((const __attribute__((address_space(1))) unsigned int*)g,
                                     (__attribute__((address_space(3))) unsigned int*)l, 16, 0, 0);
}

// WTh[n][k] fp16: h-part weights. n = g*256+t (g:0=i,1=o,2=u,3=f0,4=f1), k:[0,256)=h1,[256,512)=h2
__global__ void build_WTh(_Float16* __restrict__ WTh,
    const float* __restrict__ Wiouh1, const float* __restrict__ Wfh11, const float* __restrict__ Wfh21,
    const float* __restrict__ Wiouh2, const float* __restrict__ Wfh12, const float* __restrict__ Wfh22)
{
    int e = blockIdx.x * 256 + threadIdx.x;   // < 1280*512
    int nn = e >> 9, k = e & 511;
    int g = nn >> 8, t = nn & 255;
    float v;
    if (k < 256) {
        v = (g < 3) ? Wiouh1[k * 768 + nn] : ((g == 3) ? Wfh11[k * 256 + t] : Wfh21[k * 256 + t]);
    } else {
        int kp = k - 256;
        v = (g < 3) ? Wiouh2[kp * 768 + nn] : ((g == 3) ? Wfh12[kp * 256 + t] : Wfh22[kp * 256 + t]);
    }
    WTh[e] = (_Float16)v;
}

// tab[id][col] f32 = emb(id,:) @ Wx_fused(:,col) + bias_total(col); emb row 0 zeroed.
__global__ __launch_bounds__(256) void build_table(float* __restrict__ tab, const float* __restrict__ emb,
    const float* __restrict__ Wioux, const float* __restrict__ Wfx,
    const float* __restrict__ bioux, const float* __restrict__ biouh1, const float* __restrict__ biouh2,
    const float* __restrict__ bfx, const float* __restrict__ bfh11, const float* __restrict__ bfh12,
    const float* __restrict__ bfh21, const float* __restrict__ bfh22)
{
    __shared__ float As[64][33];
    __shared__ float Ws[32][65];
    const int tid = threadIdx.x, tx = tid & 15, ty = tid >> 4;
    const int i0 = blockIdx.x * 64, c0 = blockIdx.y * 64;
    const int g = c0 >> 8;
    float acc[4][4];
    #pragma unroll
    for (int i = 0; i < 4; ++i)
        #pragma unroll
        for (int j = 0; j < 4; ++j) acc[i][j] = 0.f;

    for (int k0 = 0; k0 < 128; k0 += 32) {
        #pragma unroll
        for (int it = 0; it < 2; ++it) {
            int f = tid + it * 256;
            int row = f >> 3, kk = (f & 7) * 4;
            int gr = i0 + row;
            float4 av = (gr == 0) ? make_float4(0.f, 0.f, 0.f, 0.f)
                                  : *(const float4*)(emb + (size_t)gr * 128 + k0 + kk);
            As[row][kk] = av.x; As[row][kk + 1] = av.y; As[row][kk + 2] = av.z; As[row][kk + 3] = av.w;
            int k = f >> 4, cc = (f & 15) * 4;
            int col = c0 + cc;
            float4 wv = (g < 3) ? *(const float4*)(Wioux + (size_t)(k0 + k) * 768 + col)
                                : *(const float4*)(Wfx + (size_t)(k0 + k) * 256 + (col & 255));
            Ws[k][cc] = wv.x; Ws[k][cc + 1] = wv.y; Ws[k][cc + 2] = wv.z; Ws[k][cc + 3] = wv.w;
        }
        __syncthreads();
        #pragma unroll 8
        for (int k = 0; k < 32; ++k) {
            float a[4], w[4];
            #pragma unroll
            for (int i = 0; i < 4; ++i) a[i] = As[ty * 4 + i][k];
            #pragma unroll
            for (int j = 0; j < 4; ++j) w[j] = Ws[k][tx * 4 + j];
            #pragma unroll
            for (int i = 0; i < 4; ++i)
                #pragma unroll
                for (int j = 0; j < 4; ++j) acc[i][j] = fmaf(a[i], w[j], acc[i][j]);
        }
        __syncthreads();
    }
    #pragma unroll
    for (int j = 0; j < 4; ++j) {
        int col = c0 + tx * 4 + j; int t = col & 255;
        float bs = (g < 3) ? (bioux[col] + biouh1[col] + biouh2[col])
                 : (g == 3) ? (bfx[t] + bfh11[t] + bfh12[t])
                            : (bfx[t] + bfh21[t] + bfh22[t]);
        #pragma unroll
        for (int i = 0; i < 4; ++i)
            tab[(size_t)(i0 + ty * 4 + i) * 1280 + col] = acc[i][j] + bs;
    }
}

// Level-0 result depends only on token id: H0h/H0c[id][t]
__global__ void build_h0c0(const float* __restrict__ tab, _Float16* __restrict__ H0h, float* __restrict__ H0c) {
    int id = blockIdx.x, t = threadIdx.x;
    const float* tp = tab + (size_t)id * 1280 + t;
    float vi = sigm(tp[0]), vo = sigm(tp[256]), vu = tanh_f(tp[512]);
    float c = vi * vu;
    H0h[id * 256 + t] = (_Float16)(vo * tanh_f(c));
    H0c[id * 256 + t] = c;
}

// Tree-level cell vG (m97-structure): BOTH A and B staged via global_load_lds into a
// 42KB double buffer, BK=32, one barrier per K-step. Block = 4 waves x (RT*16) rows
// x 16 t-cols x 5 gates. LDS tiles XOR-swizzled on 16B slots (2-way = free):
//   A: slot j of local row r holds k-seg j ^ (r&3) ^ ((r>>2)&3)
//   B: slot j of n-row nr holds k-seg j ^ ((nr>>1)&3)   [R8-measured 0 conflicts]
// XCD chunking: same-XCD consecutive blocks share row-block x (A reuse + write combine).
template<bool LVL1, int RT>
__global__ __launch_bounds__(256, 3) void cellG(
    const _Float16* __restrict__ WTh, const float* __restrict__ tab,
    const int* __restrict__ ids,
    const _Float16* __restrict__ h_prev, const float* __restrict__ c_prev,
    _Float16* __restrict__ h_out, float* __restrict__ c_out,
    int n, int ln, int off, int nx)
{
    constexpr int BM = RT * 64;
    __shared__ __align__(16) char Asm[2][BM * 64];     // A: BM rows x 32k x 2B
    __shared__ __align__(16) char Bsm[2][5120];        // B: 80 n-rows x 32k x 2B
    const int tid = threadIdx.x, lane = tid & 63, wid = tid >> 6;
    const int l15 = lane & 15, lg = lane >> 4;

    // block mapping: same-XCD consecutive blocks share x
    int bid = blockIdx.x, x, y;
    if ((nx & 7) == 0) { int xcd = bid & 7, rank = bid >> 3; x = xcd * (nx >> 3) + (rank >> 4); y = rank & 15; }
    else { x = bid >> 4; y = bid & 15; }
    const int rowB = x * BM;
    const int t0 = y * 16;

    // ---- A staging sources: thread stages RT slots; load i covers local row
    //      rl = (wid*RT+i)*16 + (lane>>2), slot j = lane&3
    const int xs = ((lane >> 2) & 3) ^ ((lane >> 4) & 3);   // X(rl) (lane-determined)
    const unsigned segOff = (unsigned)((((lane & 3) ^ xs)) * 16);
    unsigned srcA[RT], srcB1_[LVL1 ? RT : 1];
    #pragma unroll
    for (int i = 0; i < RT; ++i) {
        int rl = (wid * RT + i) * 16 + (lane >> 2);
        int r = rowB + rl;
        if constexpr (LVL1) {
            int b = r >> 7, j2 = r & 127;
            srcA[i]   = (unsigned)ids[b * NODES_ + 2 * j2] * 512u + segOff;      // H0h row=512B
            srcB1_[i] = (unsigned)ids[b * NODES_ + 2 * j2 + 1] * 512u + segOff;
        } else {
            srcA[i] = (unsigned)r * 1024u + segOff;                               // [h1|h2]=1024B
        }
    }
    // ---- B staging sources (f=tid, and f=256+tid for tid<64)
    unsigned bsrc0, bsrc1 = 0;
    {
        int nr = tid >> 2, j = tid & 3;
        int ng = (nr >> 4) * 256 + t0 + (nr & 15);
        bsrc0 = (unsigned)((ng * 512 + ((j ^ ((nr >> 1) & 3)) * 8)) * 2);
        if (tid < 64) {
            int ng2 = 1024 + t0 + (tid >> 2);
            int seg2 = (tid & 3) ^ ((tid >> 3) & 3);
            bsrc1 = (unsigned)((ng2 * 512 + seg2 * 8) * 2);
        }
    }
    const char* hPB = (const char*)h_prev;
    const char* wPB = (const char*)WTh;

    f32x4 acc[RT][5];
    #pragma unroll
    for (int rt = 0; rt < RT; ++rt)
        #pragma unroll
        for (int g = 0; g < 5; ++g) acc[rt][g] = (f32x4)0.f;

    const int xA = (l15 & 3) ^ ((l15 >> 2) & 3);
    const int xB = (l15 >> 1) & 3;

    // ---- prologue: stage step 0 into buf 0
    #pragma unroll
    for (int i = 0; i < RT; ++i)
        gload16(hPB + srcA[i], &Asm[0][(wid * RT + i) * 1024 + lane * 16]);
    gload16(wPB + bsrc0, &Bsm[0][wid * 1024 + lane * 16]);
    if (tid < 64) gload16(wPB + bsrc1, &Bsm[0][4096 + lane * 16]);
    __syncthreads();

    // ---- 16 K-steps, one barrier each; stage(S+1) overlaps compute(S)
    #pragma unroll
    for (int S = 0; S < 16; ++S) {
        const int cur = S & 1, nxt = cur ^ 1;
        if (S < 15) {
            const unsigned k1b = (unsigned)(S + 1) * 64u;   // k-offset bytes (32 halves)
            #pragma unroll
            for (int i = 0; i < RT; ++i) {
                unsigned sa;
                if constexpr (LVL1)
                    sa = (S + 1 < 8) ? (srcA[i] + k1b) : (srcB1_[i] + k1b - 512u);
                else
                    sa = srcA[i] + k1b;
                gload16(hPB + sa, &Asm[nxt][(wid * RT + i) * 1024 + lane * 16]);
            }
            gload16(wPB + bsrc0 + k1b, &Bsm[nxt][wid * 1024 + lane * 16]);
            if (tid < 64) gload16(wPB + bsrc1 + k1b, &Bsm[nxt][4096 + lane * 16]);
        }
        half8 aF[RT];
        #pragma unroll
        for (int rt = 0; rt < RT; ++rt)
            aF[rt] = *(const half8*)&Asm[cur][(wid * RT * 16 + rt * 16 + l15) * 64 + ((lg ^ xA) * 16)];
        #pragma unroll
        for (int g = 0; g < 5; ++g) {
            half8 bF = *(const half8*)&Bsm[cur][(g * 16 + l15) * 64 + ((lg ^ xB) * 16)];
            #pragma unroll
            for (int rt = 0; rt < RT; ++rt)
                acc[rt][g] = __builtin_amdgcn_mfma_f32_16x16x32_f16(aF[rt], bF, acc[rt][g], 0, 0, 0);
        }
        __syncthreads();
    }

    // ---- fused epilogue. D: col = lane&15, row = (lane>>4)*4 + q
    const int tcol = t0 + l15;
    #pragma unroll
    for (int rt = 0; rt < RT; ++rt) {
        #pragma unroll
        for (int q = 0; q < 4; ++q) {
            int row = rowB + wid * (RT * 16) + rt * 16 + lg * 4 + q;
            int b = row >> ln, j = row & (n - 1);
            int id = ids[b * NODES_ + off + j];
            const float* tp = tab + (size_t)id * 1280 + tcol;
            float c1, c2;
            if constexpr (LVL1) {
                int bb = row >> 7, jj = row & 127;
                c1 = c_prev[(size_t)ids[bb * NODES_ + 2 * jj] * 256 + tcol];
                c2 = c_prev[(size_t)ids[bb * NODES_ + 2 * jj + 1] * 256 + tcol];
            } else {
                const float* cpp = c_prev + (size_t)row * 512 + tcol;
                c1 = cpp[0]; c2 = cpp[256];
            }
            float vi  = sigm(acc[rt][0][q] + tp[0]);
            float vo  = sigm(acc[rt][1][q] + tp[256]);
            float vu  = tanh_f(acc[rt][2][q] + tp[512]);
            float vf0 = sigm(acc[rt][3][q] + tp[768]);
            float vf1 = sigm(acc[rt][4][q] + tp[1024]);
            float c = vi * vu + vf0 * c1 + vf1 * c2;
            size_t ob = (size_t)row * 256 + tcol;
            h_out[ob] = (_Float16)(vo * tanh_f(c));
            c_out[ob] = c;
        }
    }
}

// pred[b] = relu(h_root[b] @ Wl1 + bl1) @ Wl2 + bl2
__global__ void head_kernel(const _Float16* __restrict__ hroot,
    const float* __restrict__ Wl1, const float* __restrict__ bl1,
    const float* __restrict__ Wl2, const float* __restrict__ bl2,
    float* __restrict__ out)
{
    __shared__ float hrow[H_];
    __shared__ float red[256];
    int b = blockIdx.x; int tid = threadIdx.x;
    hrow[tid] = (float)hroot[(size_t)b * H_ + tid];
    __syncthreads();
    float v = 0.f;
    if (tid < 100) {
        float s = bl1[tid];
        for (int k = 0; k < H_; ++k) s = fmaf(hrow[k], Wl1[k * 100 + tid], s);
        v = fmaxf(s, 0.f) * Wl2[tid];
    }
    red[tid] = v;
    __syncthreads();
    for (int s = 128; s > 0; s >>= 1) { if (tid < s) red[tid] += red[tid + s]; __syncthreads(); }
    if (tid == 0) out[b] = red[0] + bl2[0];
}

extern "C" void kernel_launch(void* const* d_in, const int* in_sizes, int n_in,
                              void* d_out, int out_size, void* d_ws, size_t ws_size,
                              hipStream_t stream) {
    const int*   ids    = (const int*)d_in[0];
    const float* emb    = (const float*)d_in[1];
    const float* Wioux  = (const float*)d_in[2];
    const float* bioux  = (const float*)d_in[3];
    const float* Wiouh1 = (const float*)d_in[4];
    const float* biouh1 = (const float*)d_in[5];
    const float* Wiouh2 = (const float*)d_in[6];
    const float* biouh2 = (const float*)d_in[7];
    const float* Wfx    = (const float*)d_in[8];
    const float* bfx    = (const float*)d_in[9];
    const float* Wfh11  = (const float*)d_in[10];
    const float* bfh11  = (const float*)d_in[11];
    const float* Wfh12  = (const float*)d_in[12];
    const float* bfh12  = (const float*)d_in[13];
    const float* Wfh21  = (const float*)d_in[14];
    const float* bfh21  = (const float*)d_in[15];
    const float* Wfh22  = (const float*)d_in[16];
    const float* bfh22  = (const float*)d_in[17];
    const float* Wl1    = (const float*)d_in[18];
    const float* bl1    = (const float*)d_in[19];
    const float* Wl2    = (const float*)d_in[20];
    const float* bl2    = (const float*)d_in[21];
    float* out = (float*)d_out;

    // ws layout (bytes)
    char* wsb = (char*)d_ws;
    _Float16* WTh = (_Float16*)(wsb);                    //  1,310,720
    float*    tab = (float*)(wsb + 1310720);             // 10,485,760
    _Float16* H0h = (_Float16*)(wsb + 11796480);         //  1,048,576
    float*    H0c = (float*)(wsb + 12845056);            //  2,097,152
    _Float16* hA  = (_Float16*)(wsb + 14942208);         //  8,388,608
    _Float16* hB  = (_Float16*)(wsb + 23330816);         // 16,777,216
    float*    cA  = (float*)(wsb + 40108032);            // 16,777,216
    float*    cB  = (float*)(wsb + 56885248);            // 33,554,432

    build_WTh<<<dim3(2560), 256, 0, stream>>>(WTh, Wiouh1, Wfh11, Wfh21, Wiouh2, Wfh12, Wfh22);
    build_table<<<dim3(32, 20), 256, 0, stream>>>(tab, emb, Wioux, Wfx,
        bioux, biouh1, biouh2, bfx, bfh11, bfh12, bfh21, bfh22);
    build_h0c0<<<dim3(2048), 256, 0, stream>>>(tab, H0h, H0c);

    // level 1: M=32768 rows, nx=128
    cellG<true, 4><<<dim3(2048), 256, 0, stream>>>(WTh, tab, ids, H0h, H0c, hB, cB, 128, 7, 256, 128);

    _Float16 *hp = hB, *hn = hA;
    float    *cp = cB, *cn = cA;
    int off = 384, n = 64, ln = 6;
    for (int lvl = 2; lvl <= 8; ++lvl) {
        int M = B_ * n;
        if (M >= 2048) {                 // lvl 2-5: RT=4, BM=256
            int nx = M / 256;
            cellG<false, 4><<<dim3(nx * 16), 256, 0, stream>>>(WTh, tab, ids, hp, cp, hn, cn, n, ln, off, nx);
        } else if (M >= 1024) {          // lvl 6: RT=2, BM=128
            int nx = M / 128;
            cellG<false, 2><<<dim3(nx * 16), 256, 0, stream>>>(WTh, tab, ids, hp, cp, hn, cn, n, ln, off, nx);
        } else {                         // lvl 7-8: RT=1, BM=64
            int nx = M / 64;
            cellG<false, 1><<<dim3(nx * 16), 256, 0, stream>>>(WTh, tab, ids, hp, cp, hn, cn, n, ln, off, nx);
        }
        off += n; n >>= 1; --ln;
        _Float16* t1 = hp; hp = hn; hn = t1;
        float*    t2 = cp; cp = cn; cn = t2;
    }

    head_kernel<<<dim3(256), 256, 0, stream>>>(hp, Wl1, bl1, Wl2, bl2, out);
}

// Round 13
// 277.990 us; speedup vs baseline: 2.7289x; 1.0421x over previous
//
#include <hip/hip_runtime.h>
#include <math.h>

#define B_ 256
#define L_ 256
#define V_ 2048
#define DIN_ 128
#define H_ 256
#define NODES_ 511

typedef _Float16 half8 __attribute__((ext_vector_type(8)));
typedef float f32x4 __attribute__((ext_vector_type(4)));

__device__ __forceinline__ float sigm(float x) { return 1.f / (1.f + __expf(-x)); }
__device__ __forceinline__ float tanh_f(float x) {
    float xc = fminf(fmaxf(x, -15.f), 15.f);
    float e = __expf(2.f * xc);
    return (e - 1.f) / (e + 1.f);
}
__device__ __forceinline__ void gload16(const void* g, void* l) {
    __builtin_amdgcn_global_load_lds((const __attribute__((address_space(1))) unsigned int*)g,
                                     (__attribute__((address_space(3))) unsigned int*)l, 16, 0, 0);
}
template<int N> __device__ __forceinline__ void vwaitN() {
    asm volatile("s_waitcnt vmcnt(%0)" :: "i"(N) : "memory");
}

// WTh[n][k] fp16: h-part weights. n = g*256+t (g:0=i,1=o,2=u,3=f0,4=f1), k:[0,256)=h1,[256,512)=h2
__global__ void build_WTh(_Float16* __restrict__ WTh,
    const float* __restrict__ Wiouh1, const float* __restrict__ Wfh11, const float* __restrict__ Wfh21,
    const float* __restrict__ Wiouh2, const float* __restrict__ Wfh12, const float* __restrict__ Wfh22)
{
    int e = blockIdx.x * 256 + threadIdx.x;   // < 1280*512
    int nn = e >> 9, k = e & 511;
    int g = nn >> 8, t = nn & 255;
    float v;
    if (k < 256) {
        v = (g < 3) ? Wiouh1[k * 768 + nn] : ((g == 3) ? Wfh11[k * 256 + t] : Wfh21[k * 256 + t]);
    } else {
        int kp = k - 256;
        v = (g < 3) ? Wiouh2[kp * 768 + nn] : ((g == 3) ? Wfh12[kp * 256 + t] : Wfh22[kp * 256 + t]);
    }
    WTh[e] = (_Float16)v;
}

// tab[id][col] f32 = emb(id,:) @ Wx_fused(:,col) + bias_total(col); emb row 0 zeroed.
__global__ __launch_bounds__(256) void build_table(float* __restrict__ tab, const float* __restrict__ emb,
    const float* __restrict__ Wioux, const float* __restrict__ Wfx,
    const float* __restrict__ bioux, const float* __restrict__ biouh1, const float* __restrict__ biouh2,
    const float* __restrict__ bfx, const float* __restrict__ bfh11, const float* __restrict__ bfh12,
    const float* __restrict__ bfh21, const float* __restrict__ bfh22)
{
    __shared__ float As[64][33];
    __shared__ float Ws[32][65];
    const int tid = threadIdx.x, tx = tid & 15, ty = tid >> 4;
    const int i0 = blockIdx.x * 64, c0 = blockIdx.y * 64;
    const int g = c0 >> 8;
    float acc[4][4];
    #pragma unroll
    for (int i = 0; i < 4; ++i)
        #pragma unroll
        for (int j = 0; j < 4; ++j) acc[i][j] = 0.f;

    for (int k0 = 0; k0 < 128; k0 += 32) {
        #pragma unroll
        for (int it = 0; it < 2; ++it) {
            int f = tid + it * 256;
            int row = f >> 3, kk = (f & 7) * 4;
            int gr = i0 + row;
            float4 av = (gr == 0) ? make_float4(0.f, 0.f, 0.f, 0.f)
                                  : *(const float4*)(emb + (size_t)gr * 128 + k0 + kk);
            As[row][kk] = av.x; As[row][kk + 1] = av.y; As[row][kk + 2] = av.z; As[row][kk + 3] = av.w;
            int k = f >> 4, cc = (f & 15) * 4;
            int col = c0 + cc;
            float4 wv = (g < 3) ? *(const float4*)(Wioux + (size_t)(k0 + k) * 768 + col)
                                : *(const float4*)(Wfx + (size_t)(k0 + k) * 256 + (col & 255));
            Ws[k][cc] = wv.x; Ws[k][cc + 1] = wv.y; Ws[k][cc + 2] = wv.z; Ws[k][cc + 3] = wv.w;
        }
        __syncthreads();
        #pragma unroll 8
        for (int k = 0; k < 32; ++k) {
            float a[4], w[4];
            #pragma unroll
            for (int i = 0; i < 4; ++i) a[i] = As[ty * 4 + i][k];
            #pragma unroll
            for (int j = 0; j < 4; ++j) w[j] = Ws[k][tx * 4 + j];
            #pragma unroll
            for (int i = 0; i < 4; ++i)
                #pragma unroll
                for (int j = 0; j < 4; ++j) acc[i][j] = fmaf(a[i], w[j], acc[i][j]);
        }
        __syncthreads();
    }
    #pragma unroll
    for (int j = 0; j < 4; ++j) {
        int col = c0 + tx * 4 + j; int t = col & 255;
        float bs = (g < 3) ? (bioux[col] + biouh1[col] + biouh2[col])
                 : (g == 3) ? (bfx[t] + bfh11[t] + bfh12[t])
                            : (bfx[t] + bfh21[t] + bfh22[t]);
        #pragma unroll
        for (int i = 0; i < 4; ++i)
            tab[(size_t)(i0 + ty * 4 + i) * 1280 + col] = acc[i][j] + bs;
    }
}

// Level-0 result depends only on token id: H0h/H0c[id][t]
__global__ void build_h0c0(const float* __restrict__ tab, _Float16* __restrict__ H0h, float* __restrict__ H0c) {
    int id = blockIdx.x, t = threadIdx.x;
    const float* tp = tab + (size_t)id * 1280 + t;
    float vi = sigm(tp[0]), vo = sigm(tp[256]), vu = tanh_f(tp[512]);
    float c = vi * vu;
    H0h[id * 256 + t] = (_Float16)(vo * tanh_f(c));
    H0c[id * 256 + t] = c;
}

// Tree-level cell vH: m97-structure + T3/T4 counted-vmcnt 3-buffer pipeline.
// Block = 4 waves x (RT*16) rows x 16 t-cols x 5 gates. BK=32, 16 K-steps.
// Both LDS tiles use the R8-measured 0-conflict swizzle: slot j of row r holds
// k-seg j ^ ((r>>1)&3); reads use slot = lg ^ ((l15>>1)&3).
// Pipeline: stage(S+2) at step S; end-of-step wait = vmcnt(loads-of-one-step), NOT 0.
template<bool LVL1, int RT>
__global__ __launch_bounds__(256, (RT >= 4 ? 2 : 4)) void cellH(
    const _Float16* __restrict__ WTh, const float* __restrict__ tab,
    const int* __restrict__ ids,
    const _Float16* __restrict__ h_prev, const float* __restrict__ c_prev,
    _Float16* __restrict__ h_out, float* __restrict__ c_out,
    int n, int ln, int off, int nx)
{
    constexpr int BM = RT * 64;
    constexpr int AB = BM * 64;                         // A bytes per buffer
    __shared__ __align__(16) char Asm[3][AB];
    __shared__ __align__(16) char Bsm[3][5120];
    const int tid = threadIdx.x, lane = tid & 63, wid = tid >> 6;
    const int l15 = lane & 15, lg = lane >> 4;

    // block mapping: same-XCD consecutive blocks share row-block x
    int bid = blockIdx.x, x, y;
    if ((nx & 7) == 0) { int xcd = bid & 7, rank = bid >> 3; x = xcd * (nx >> 3) + (rank >> 4); y = rank & 15; }
    else { x = bid >> 4; y = bid & 15; }
    const int rowB = x * BM;
    const int t0 = y * 16;

    // ---- A staging sources: thread stages RT slots; load i covers local row
    //      rl = (wid*RT+i)*16 + (lane>>2), slot j = lane&3; seg = j ^ ((rl>>1)&3)
    const unsigned segOff = (unsigned)((((lane & 3) ^ ((lane >> 3) & 3))) * 16);
    unsigned srcA[RT], srcB1_[LVL1 ? RT : 1];
    #pragma unroll
    for (int i = 0; i < RT; ++i) {
        int rl = (wid * RT + i) * 16 + (lane >> 2);
        int r = rowB + rl;
        if constexpr (LVL1) {
            int b = r >> 7, j2 = r & 127;
            srcA[i]   = (unsigned)ids[b * NODES_ + 2 * j2] * 512u + segOff;      // H0h row=512B
            srcB1_[i] = (unsigned)ids[b * NODES_ + 2 * j2 + 1] * 512u + segOff;
        } else {
            srcA[i] = (unsigned)r * 1024u + segOff;                               // [h1|h2]=1024B
        }
    }
    // ---- B staging sources (main: all threads; extra row block: wave 0)
    unsigned bsrc0, bsrc1 = 0;
    {
        int nr = tid >> 2, j = tid & 3;
        int ng = (nr >> 4) * 256 + t0 + (nr & 15);
        bsrc0 = (unsigned)((ng * 512 + ((j ^ ((nr >> 1) & 3)) * 8)) * 2);
        if (wid == 0) {
            int ng2 = 1024 + t0 + (tid >> 2);
            int seg2 = (tid & 3) ^ ((tid >> 3) & 3);
            bsrc1 = (unsigned)((ng2 * 512 + seg2 * 8) * 2);
        }
    }
    const char* hPB = (const char*)h_prev;
    const char* wPB = (const char*)WTh;

    f32x4 acc[RT][5];
    #pragma unroll
    for (int rt = 0; rt < RT; ++rt)
        #pragma unroll
        for (int g = 0; g < 5; ++g) acc[rt][g] = (f32x4)0.f;

    const int xw = (l15 >> 1) & 3;                      // proven 0-conflict read XOR

    // ---- staging (st = K-step to stage, buf = target buffer)
    auto STAGE = [&](int st, int buf) {
        #pragma unroll
        for (int i = 0; i < RT; ++i) {
            unsigned sa;
            if constexpr (LVL1)
                sa = (st < 8) ? (srcA[i] + (unsigned)st * 64u) : (srcB1_[i] + (unsigned)(st - 8) * 64u);
            else
                sa = srcA[i] + (unsigned)st * 64u;
            gload16(hPB + sa, &Asm[buf][(wid * RT + i) * 1024 + lane * 16]);
        }
        gload16(wPB + bsrc0 + (unsigned)st * 64u, &Bsm[buf][tid * 16]);
        if (wid == 0) gload16(wPB + bsrc1 + (unsigned)st * 64u, &Bsm[buf][4096 + tid * 16]);
    };
    auto COMPUTE = [&](int buf) {
        half8 aF[RT];
        #pragma unroll
        for (int rt = 0; rt < RT; ++rt)
            aF[rt] = *(const half8*)&Asm[buf][(wid * RT * 16 + rt * 16 + l15) * 64 + ((lg ^ xw) * 16)];
        #pragma unroll
        for (int g = 0; g < 5; ++g) {
            half8 bF = *(const half8*)&Bsm[buf][(g * 16 + l15) * 64 + ((lg ^ xw) * 16)];
            #pragma unroll
            for (int rt = 0; rt < RT; ++rt)
                acc[rt][g] = __builtin_amdgcn_mfma_f32_16x16x32_f16(aF[rt], bF, acc[rt][g], 0, 0, 0);
        }
    };
    auto WAITB = [&](bool counted) {
        if (counted) { if (wid == 0) vwaitN<RT + 2>(); else vwaitN<RT + 1>(); }
        else vwaitN<0>();
        __builtin_amdgcn_s_barrier();
        __builtin_amdgcn_sched_barrier(0);
    };

    // ---- prologue: stage steps 0,1; wait for step-0 loads only (counted)
    STAGE(0, 0);
    STAGE(1, 1);
    WAITB(true);

    // ---- 16 K-steps; stage(S+2) overlaps compute(S); counted waits between steps
    #pragma unroll
    for (int S = 0; S < 16; ++S) {
        if (S + 2 < 16) STAGE(S + 2, (S + 2) % 3);
        COMPUTE(S % 3);
        if (S < 15) WAITB(S + 2 < 16);
    }

    // ---- fused epilogue. D: col = lane&15, row = (lane>>4)*4 + q
    const int tcol = t0 + l15;
    #pragma unroll
    for (int rt = 0; rt < RT; ++rt) {
        #pragma unroll
        for (int q = 0; q < 4; ++q) {
            int row = rowB + wid * (RT * 16) + rt * 16 + lg * 4 + q;
            int b = row >> ln, j = row & (n - 1);
            int id = ids[b * NODES_ + off + j];
            const float* tp = tab + (size_t)id * 1280 + tcol;
            float c1, c2;
            if constexpr (LVL1) {
                int bb = row >> 7, jj = row & 127;
                c1 = c_prev[(size_t)ids[bb * NODES_ + 2 * jj] * 256 + tcol];
                c2 = c_prev[(size_t)ids[bb * NODES_ + 2 * jj + 1] * 256 + tcol];
            } else {
                const float* cpp = c_prev + (size_t)row * 512 + tcol;
                c1 = cpp[0]; c2 = cpp[256];
            }
            float vi  = sigm(acc[rt][0][q] + tp[0]);
            float vo  = sigm(acc[rt][1][q] + tp[256]);
            float vu  = tanh_f(acc[rt][2][q] + tp[512]);
            float vf0 = sigm(acc[rt][3][q] + tp[768]);
            float vf1 = sigm(acc[rt][4][q] + tp[1024]);
            float c = vi * vu + vf0 * c1 + vf1 * c2;
            size_t ob = (size_t)row * 256 + tcol;
            h_out[ob] = (_Float16)(vo * tanh_f(c));
            c_out[ob] = c;
        }
    }
}

// pred[b] = relu(h_root[b] @ Wl1 + bl1) @ Wl2 + bl2
__global__ void head_kernel(const _Float16* __restrict__ hroot,
    const float* __restrict__ Wl1, const float* __restrict__ bl1,
    const float* __restrict__ Wl2, const float* __restrict__ bl2,
    float* __restrict__ out)
{
    __shared__ float hrow[H_];
    __shared__ float red[256];
    int b = blockIdx.x; int tid = threadIdx.x;
    hrow[tid] = (float)hroot[(size_t)b * H_ + tid];
    __syncthreads();
    float v = 0.f;
    if (tid < 100) {
        float s = bl1[tid];
        for (int k = 0; k < H_; ++k) s = fmaf(hrow[k], Wl1[k * 100 + tid], s);
        v = fmaxf(s, 0.f) * Wl2[tid];
    }
    red[tid] = v;
    __syncthreads();
    for (int s = 128; s > 0; s >>= 1) { if (tid < s) red[tid] += red[tid + s]; __syncthreads(); }
    if (tid == 0) out[b] = red[0] + bl2[0];
}

extern "C" void kernel_launch(void* const* d_in, const int* in_sizes, int n_in,
                              void* d_out, int out_size, void* d_ws, size_t ws_size,
                              hipStream_t stream) {
    const int*   ids    = (const int*)d_in[0];
    const float* emb    = (const float*)d_in[1];
    const float* Wioux  = (const float*)d_in[2];
    const float* bioux  = (const float*)d_in[3];
    const float* Wiouh1 = (const float*)d_in[4];
    const float* biouh1 = (const float*)d_in[5];
    const float* Wiouh2 = (const float*)d_in[6];
    const float* biouh2 = (const float*)d_in[7];
    const float* Wfx    = (const float*)d_in[8];
    const float* bfx    = (const float*)d_in[9];
    const float* Wfh11  = (const float*)d_in[10];
    const float* bfh11  = (const float*)d_in[11];
    const float* Wfh12  = (const float*)d_in[12];
    const float* bfh12  = (const float*)d_in[13];
    const float* Wfh21  = (const float*)d_in[14];
    const float* bfh21  = (const float*)d_in[15];
    const float* Wfh22  = (const float*)d_in[16];
    const float* bfh22  = (const float*)d_in[17];
    const float* Wl1    = (const float*)d_in[18];
    const float* bl1    = (const float*)d_in[19];
    const float* Wl2    = (const float*)d_in[20];
    const float* bl2    = (const float*)d_in[21];
    float* out = (float*)d_out;

    // ws layout (bytes)
    char* wsb = (char*)d_ws;
    _Float16* WTh = (_Float16*)(wsb);                    //  1,310,720
    float*    tab = (float*)(wsb + 1310720);             // 10,485,760
    _Float16* H0h = (_Float16*)(wsb + 11796480);         //  1,048,576
    float*    H0c = (float*)(wsb + 12845056);            //  2,097,152
    _Float16* hA  = (_Float16*)(wsb + 14942208);         //  8,388,608
    _Float16* hB  = (_Float16*)(wsb + 23330816);         // 16,777,216
    float*    cA  = (float*)(wsb + 40108032);            // 16,777,216
    float*    cB  = (float*)(wsb + 56885248);            // 33,554,432

    build_WTh<<<dim3(2560), 256, 0, stream>>>(WTh, Wiouh1, Wfh11, Wfh21, Wiouh2, Wfh12, Wfh22);
    build_table<<<dim3(32, 20), 256, 0, stream>>>(tab, emb, Wioux, Wfx,
        bioux, biouh1, biouh2, bfx, bfh11, bfh12, bfh21, bfh22);
    build_h0c0<<<dim3(2048), 256, 0, stream>>>(tab, H0h, H0c);

    // level 1: M=32768 rows, nx=128
    cellH<true, 4><<<dim3(2048), 256, 0, stream>>>(WTh, tab, ids, H0h, H0c, hB, cB, 128, 7, 256, 128);

    _Float16 *hp = hB, *hn = hA;
    float    *cp = cB, *cn = cA;
    int off = 384, n = 64, ln = 6;
    for (int lvl = 2; lvl <= 8; ++lvl) {
        int M = B_ * n;
        if (M >= 2048) {                 // lvl 2-5: RT=4, BM=256
            int nx = M / 256;
            cellH<false, 4><<<dim3(nx * 16), 256, 0, stream>>>(WTh, tab, ids, hp, cp, hn, cn, n, ln, off, nx);
        } else if (M >= 1024) {          // lvl 6: RT=2, BM=128
            int nx = M / 128;
            cellH<false, 2><<<dim3(nx * 16), 256, 0, stream>>>(WTh, tab, ids, hp, cp, hn, cn, n, ln, off, nx);
        } else {                         // lvl 7-8: RT=1, BM=64
            int nx = M / 64;
            cellH<false, 1><<<dim3(nx * 16), 256, 0, stream>>>(WTh, tab, ids, hp, cp, hn, cn, n, ln, off, nx);
        }
        off += n; n >>= 1; --ln;
        _Float16* t1 = hp; hp = hn; hn = t1;
        float*    t2 = cp; cp = cn; cn = t2;
    }

    head_kernel<<<dim3(256), 256, 0, stream>>>(hp, Wl1, bl1, Wl2, bl2, out);
}